// Round 8
// baseline (270.184 us; speedup 1.0000x reference)
//
#include <hip/hip_runtime.h>
#include <math.h>
#include <stdint.h>

typedef __bf16 bf16_t;
typedef __bf16 bf16x2 __attribute__((ext_vector_type(2)));
typedef __bf16 bf16x4 __attribute__((ext_vector_type(4)));
typedef __bf16 bf16x8 __attribute__((ext_vector_type(8)));
typedef float f32x4 __attribute__((ext_vector_type(4)));
typedef float f32x16 __attribute__((ext_vector_type(16)));

#define NB   32
#define SEQ  2048
#define HD   128
#define SCALE 0.08838834764831845f
#define LOG2E 1.4426950408889634f

__device__ __forceinline__ float fast_exp2(float x) {
#if __has_builtin(__builtin_amdgcn_exp2f)
  return __builtin_amdgcn_exp2f(x);
#else
  return exp2f(x);
#endif
}

// ============================ prep kernel =================================
// blocks 0..2047:    Qs = bf16(Q * SCALE * LOG2E)   (exp2-unit scores)
// blocks 2048..4095: Kb = bf16(K)
// blocks 4096..6143: Vt = bf16(V) transposed [B][D][S], conflict-free f32 tile
__global__ __launch_bounds__(256) void prep_kernel(
    const float* __restrict__ Q, const float* __restrict__ K,
    const float* __restrict__ V, bf16_t* __restrict__ Qs,
    bf16_t* __restrict__ Kb, bf16_t* __restrict__ Vt)
{
  const int b = blockIdx.x;
  const int tid = threadIdx.x;
  if (b < 4096) {
    const bool isQ = (b < 2048);
    const float* src = isQ ? Q : K;
    bf16_t* dst = isQ ? Qs : Kb;
    const float sc = isQ ? (SCALE * LOG2E) : 1.0f;
    size_t base4 = (size_t)(isQ ? b : b - 2048) * 1024;
#pragma unroll
    for (int i = 0; i < 4; ++i) {
      size_t idx = base4 + tid + i * 256;
      float4 x = ((const float4*)src)[idx];
      bf16x4 y;
      y[0] = (bf16_t)(x.x * sc); y[1] = (bf16_t)(x.y * sc);
      y[2] = (bf16_t)(x.z * sc); y[3] = (bf16_t)(x.w * sc);
      ((bf16x4*)dst)[idx] = y;
    }
  } else {
    // f32 tile, stride 65: bank(s,d) = (s + d) % 32 -> conflict-free both sides.
    __shared__ float tile[64][65];  // 16.6 KB
    const int bt = b - 4096;
    const int batch = bt >> 6;
    const int rem = bt & 63;
    const int s0 = (rem >> 1) * 64;
    const int d0 = (rem & 1) * 64;
#pragma unroll
    for (int i = 0; i < 4; ++i) {
      int e = tid + i * 256;
      int s = e >> 4, dq = e & 15;
      float4 x = *(const float4*)&V[((size_t)batch * SEQ + s0 + s) * HD + d0 + dq * 4];
      tile[s][dq * 4 + 0] = x.x;
      tile[s][dq * 4 + 1] = x.y;
      tile[s][dq * 4 + 2] = x.z;
      tile[s][dq * 4 + 3] = x.w;
    }
    __syncthreads();
#pragma unroll
    for (int i = 0; i < 2; ++i) {
      int g = tid + i * 256;
      int d = g >> 3, sg = g & 7;
      bf16x8 w;
#pragma unroll
      for (int j = 0; j < 8; ++j) w[j] = (bf16_t)tile[sg * 8 + j][d];
      *(bf16x8*)&Vt[((size_t)batch * HD + d0 + d) * SEQ + s0 + sg * 8] = w;
    }
  }
}

// ============================ main kernel =================================
// fa13 = fa12 per-wave compute (32x32x16 MFMA, split-K pairs, in-register P)
// scaled to 8 waves / 512 threads / 128 q-rows per block:
//   - waves/SIMD 2 -> 4 (the TLP that fa12's latency-bound profile lacked)
//   - one 64-row KV tile feeds 128 q-rows (staging per FLOP halves)
//   - grid 512 = exactly 2 blocks/CU x 256 CU, single round
//   - epilogue pair-merge through reused staging LDS (stride-132 f32 rows)
__global__ __launch_bounds__(512, 4) void fa13_kernel(
    const bf16_t* __restrict__ Qs, const bf16_t* __restrict__ Kbf,
    const bf16_t* __restrict__ Vt, float* __restrict__ O)
{
  // aliased LDS: staging (64KB) then epilogue scratch (66KB+1KB)
  __shared__ __attribute__((aligned(16))) char smem[68608];
  bf16_t* const Ksw = (bf16_t*)smem;              // [2][64*128] bf16
  bf16_t* const Vsw = (bf16_t*)(smem + 32768);    // [2][128*64] bf16

  const int tid  = threadIdx.x;
  const int lane = tid & 63;
  const int wq   = tid >> 6;         // 0..7
  const int hi   = lane >> 5;        // half of wave
  const int q31  = lane & 31;        // q-column within 32-row q-group
  const int pair = wq >> 1;          // 0..3 : q-rows pair*32 .. pair*32+31
  const int sub  = wq & 1;           // k-half within pair
  const int koff = sub * 32;

  const int batch = blockIdx.x >> 4;
  const int qt    = blockIdx.x & 15; // q-tile of 128 rows

  const bf16_t* Qb = Qs + ((size_t)batch * SEQ + qt * 128 + pair * 32) * HD;
  const bf16_t* Kb = Kbf + (size_t)batch * SEQ * HD;
  const bf16_t* Vb = Vt + (size_t)batch * HD * SEQ;
  float*        Ob = O + ((size_t)batch * SEQ + qt * 128) * HD;

  // ---- Q fragments (B-operand): B[col=q31][k=d = dc*16 + hi*8 + j] ----
  bf16x8 bq[8];
#pragma unroll
  for (int dc = 0; dc < 8; ++dc)
    bq[dc] = *(const bf16x8*)&Qb[(size_t)q31 * HD + dc * 16 + hi * 8];

  f32x16 o[4];
#pragma unroll
  for (int dt = 0; dt < 4; ++dt)
#pragma unroll
    for (int r = 0; r < 16; ++r) o[dt][r] = 0.f;
  float m_r = -INFINITY, l_r = 0.0f;

  // ---- DMA staging: 8 waves share one 64-row KV tile (2 K + 2 V per wave) --
  auto stage = [&](int buf, int kb) {
#pragma unroll
    for (int i = 0; i < 2; ++i) {
      int row = wq * 8 + i * 4 + (lane >> 4);
      int gk = (lane & 15) ^ (row & 15);
      const bf16_t* gp = Kb + (size_t)(kb + row) * HD + gk * 8;
      __builtin_amdgcn_global_load_lds(
          (const __attribute__((address_space(1))) void*)gp,
          (__attribute__((address_space(3))) void*)&Ksw[buf * 8192 + (wq * 8 + i * 4) * 128],
          16, 0, 0);
    }
#pragma unroll
    for (int i = 0; i < 2; ++i) {
      int d = wq * 16 + i * 8 + (lane >> 3);
      int gv = (lane & 7) ^ (d & 7);
      const bf16_t* gp = Vb + (size_t)d * SEQ + kb + gv * 8;
      __builtin_amdgcn_global_load_lds(
          (const __attribute__((address_space(1))) void*)gp,
          (__attribute__((address_space(3))) void*)&Vsw[buf * 8192 + (wq * 16 + i * 8) * 64],
          16, 0, 0);
    }
  };

  stage(0, 0);

  for (int t = 0; t < SEQ / 64; ++t) {
    __syncthreads();  // drains own DMA + prior LDS reads
    if (t + 1 < SEQ / 64) stage((t + 1) & 1, (t + 1) * 64);

    const bf16_t* Ks = &Ksw[(t & 1) * 8192];
    const bf16_t* Vs = &Vsw[(t & 1) * 8192];

    // ---- S^T = K Q^T on this wave's 32-k half (log2 units) ----
    f32x16 s;
#pragma unroll
    for (int r = 0; r < 16; ++r) s[r] = 0.f;
    {
      const int row = koff + q31;
      const int rsw = row & 15;
#pragma unroll
      for (int dc = 0; dc < 8; ++dc) {
        bf16x8 ak = *(const bf16x8*)&Ks[row * 128 + (((dc * 2 + hi) ^ rsw) * 8)];
        s = __builtin_amdgcn_mfma_f32_32x32x16_bf16(ak, bq[dc], s, 0, 0, 0);
      }
    }

    // ---- softmax: row max across this wave's 32 k (lane pair l <-> l^32) ----
    float mx = s[0];
#pragma unroll
    for (int r = 1; r < 16; ++r) mx = fmaxf(mx, s[r]);
    mx = fmaxf(mx, __shfl_xor(mx, 32));

    // ---- defer-max: rescale only when max grew by > 8 (P bounded by 256) ----
    if (!__all(mx <= m_r + 8.0f)) {
      const float mnew = fmaxf(m_r, mx);
      const float alpha = fast_exp2(m_r - mnew);
      m_r = mnew;
      l_r *= alpha;
#pragma unroll
      for (int dt = 0; dt < 4; ++dt) o[dt] = o[dt] * alpha;
    }

    // ---- P = exp2(S - m), partial row sum ----
    float ls = 0.f;
#pragma unroll
    for (int r = 0; r < 16; ++r) {
      float p = fast_exp2(s[r] - m_r);
      s[r] = p; ls += p;
    }
    ls += __shfl_xor(ls, 32);
    l_r += ls;

    // ---- pack P to bf16 pairs; assemble PV B-fragments via 4 shfl_xor ----
    uint32_t pk[8];
#pragma unroll
    for (int i = 0; i < 8; ++i) {
      union { bf16x2 v; uint32_t u; } c;
      c.v[0] = (bf16_t)s[2 * i];
      c.v[1] = (bf16_t)s[2 * i + 1];
      pk[i] = c.u;
    }
    uint32_t t0 = __shfl_xor((int)(hi ? pk[0] : pk[2]), 32);
    uint32_t t1 = __shfl_xor((int)(hi ? pk[1] : pk[3]), 32);
    uint32_t t2 = __shfl_xor((int)(hi ? pk[4] : pk[6]), 32);
    uint32_t t3 = __shfl_xor((int)(hi ? pk[5] : pk[7]), 32);
    bf16x8 bp0, bp1;
    {
      union { bf16x8 v; uint32_t w[4]; } B;
      if (hi) { B.w[0] = t0; B.w[1] = t1; B.w[2] = pk[2]; B.w[3] = pk[3]; }
      else    { B.w[0] = pk[0]; B.w[1] = pk[1]; B.w[2] = t0; B.w[3] = t1; }
      bp0 = B.v;
      if (hi) { B.w[0] = t2; B.w[1] = t3; B.w[2] = pk[6]; B.w[3] = pk[7]; }
      else    { B.w[0] = pk[4]; B.w[1] = pk[5]; B.w[2] = t2; B.w[3] = t3; }
      bp1 = B.v;
    }

    // ---- O^T += V^T P^T over this wave's 32 k (2 chunks of 16) ----
    {
      const int g0 = (koff >> 3) + hi;
      const int g1 = g0 + 2;
#pragma unroll
      for (int dt = 0; dt < 4; ++dt) {
        const int d = dt * 32 + q31;
        const int dsw = d & 7;
        bf16x8 av0 = *(const bf16x8*)&Vs[d * 64 + ((g0 ^ dsw) * 8)];
        o[dt] = __builtin_amdgcn_mfma_f32_32x32x16_bf16(av0, bp0, o[dt], 0, 0, 0);
        bf16x8 av1 = *(const bf16x8*)&Vs[d * 64 + ((g1 ^ dsw) * 8)];
        o[dt] = __builtin_amdgcn_mfma_f32_32x32x16_bf16(av1, bp1, o[dt], 0, 0, 0);
      }
    }
  }

  // ================= epilogue: merge k-halves, store =================
  __syncthreads();  // all LDS reads done; staging buffers reusable as scratch
  float* const sf  = (float*)smem;          // scratch: pair * 4224 + q*132 + d
  float* const mlb = (float*)(smem + 67584);

  if (sub == 1) {
    if (hi == 0) {
      mlb[pair * 64 + q31]      = m_r;
      mlb[pair * 64 + 32 + q31] = l_r;
    }
#pragma unroll
    for (int dt = 0; dt < 4; ++dt)
#pragma unroll
      for (int r = 0; r < 16; ++r) {
        int d = dt * 32 + (r & 3) + 8 * (r >> 2) + 4 * hi;
        sf[pair * 4224 + q31 * 132 + d] = o[dt][r];
      }
  }
  __syncthreads();
  if (sub == 0) {
    float m1 = mlb[pair * 64 + q31];
    float l1 = mlb[pair * 64 + 32 + q31];
    float m = fmaxf(m_r, m1);
    float e0 = fast_exp2(m_r - m);
    float e1 = fast_exp2(m1 - m);
    float inv = 1.0f / (l_r * e0 + l1 * e1);
    float f0 = e0 * inv, f1 = e1 * inv;
#pragma unroll
    for (int dt = 0; dt < 4; ++dt)
#pragma unroll
      for (int r = 0; r < 16; ++r) {
        int d = dt * 32 + (r & 3) + 8 * (r >> 2) + 4 * hi;
        float* p = &sf[pair * 4224 + q31 * 132 + d];
        *p = o[dt][r] * f0 + *p * f1;
      }
  }
  __syncthreads();
  // cooperative coalesced store: 512 threads x 8 float4 = 128 rows x 128 d
  {
#pragma unroll
    for (int i = 0; i < 8; ++i) {
      int idx = tid + i * 512;          // 0..4095
      int q = idx >> 5;                 // 0..127
      int dg = idx & 31;                // float4 granule
      float4 v = *(const float4*)&sf[(q >> 5) * 4224 + (q & 31) * 132 + dg * 4];
      *(float4*)&Ob[(size_t)q * HD + dg * 4] = v;
    }
  }
}

// ===================== fallback (proven R2 kernel) ========================
#define BM   64
#define BN   64
#define KPAD 8
#define VPAD 8
#define PPAD 8

__global__ __launch_bounds__(256) void fa_fallback(
    const float* __restrict__ Q, const float* __restrict__ K,
    const float* __restrict__ V, float* __restrict__ O)
{
  __shared__ __attribute__((aligned(16))) bf16_t Ksh[BN][HD + KPAD];
  __shared__ __attribute__((aligned(16))) bf16_t Vsh[HD][BN + VPAD];
  __shared__ __attribute__((aligned(16))) bf16_t Psh[4][16][BN + PPAD];

  const int tid = threadIdx.x;
  const int lane = tid & 63;
  const int wq = tid >> 6;
  const int quad = lane >> 4;
  const int l15 = lane & 15;
  const int bid = blockIdx.x;
  const int batch = bid >> 5;
  const int qt = bid & 31;

  const float* Qb = Q + (size_t)batch * SEQ * HD + (size_t)qt * BM * HD;
  const float* Kb = K + (size_t)batch * SEQ * HD;
  const float* Vb = V + (size_t)batch * SEQ * HD;
  float* Ob = O + (size_t)batch * SEQ * HD + (size_t)qt * BM * HD;

  bf16x8 aq[4];
  {
    const int qrow = wq * 16 + l15;
#pragma unroll
    for (int kf = 0; kf < 4; ++kf) {
      const float* qp = Qb + (size_t)qrow * HD + kf * 32 + quad * 8;
      float4 x0 = *(const float4*)(qp);
      float4 x1 = *(const float4*)(qp + 4);
      bf16x8 a;
      a[0] = (bf16_t)(x0.x * SCALE); a[1] = (bf16_t)(x0.y * SCALE);
      a[2] = (bf16_t)(x0.z * SCALE); a[3] = (bf16_t)(x0.w * SCALE);
      a[4] = (bf16_t)(x1.x * SCALE); a[5] = (bf16_t)(x1.y * SCALE);
      a[6] = (bf16_t)(x1.z * SCALE); a[7] = (bf16_t)(x1.w * SCALE);
      aq[kf] = a;
    }
  }

  f32x4 o[8];
#pragma unroll
  for (int t = 0; t < 8; ++t) { o[t][0]=0.f; o[t][1]=0.f; o[t][2]=0.f; o[t][3]=0.f; }
  float m_r = -INFINITY, l_r = 0.0f;
  const int vkp = (tid & 31) * 2;
  const int vg = tid >> 5;
  float4 kreg[8], vreg[8];

#pragma unroll
  for (int i = 0; i < 8; ++i) {
    int v = tid + i * 256, row = v >> 5, c4 = (v & 31) * 4;
    kreg[i] = *(const float4*)(Kb + (size_t)row * HD + c4);
  }
#pragma unroll
  for (int i = 0; i < 4; ++i) {
    int d0 = (vg + i * 8) * 4;
    const float* vp0 = Vb + (size_t)vkp * HD + d0;
    vreg[2 * i] = *(const float4*)vp0;
    vreg[2 * i + 1] = *(const float4*)(vp0 + HD);
  }

  for (int kb = 0; kb < SEQ; kb += BN) {
    __syncthreads();
#pragma unroll
    for (int i = 0; i < 8; ++i) {
      int v = tid + i * 256, row = v >> 5, c4 = (v & 31) * 4;
      float4 kv = kreg[i];
      bf16x4 kk;
      kk[0]=(bf16_t)kv.x; kk[1]=(bf16_t)kv.y; kk[2]=(bf16_t)kv.z; kk[3]=(bf16_t)kv.w;
      *(bf16x4*)&Ksh[row][c4] = kk;
    }
#pragma unroll
    for (int i = 0; i < 4; ++i) {
      int d0 = (vg + i * 8) * 4;
      float4 a0 = vreg[2 * i], a1 = vreg[2 * i + 1];
      bf16x2 p0; p0[0]=(bf16_t)a0.x; p0[1]=(bf16_t)a1.x;
      bf16x2 p1; p1[0]=(bf16_t)a0.y; p1[1]=(bf16_t)a1.y;
      bf16x2 p2; p2[0]=(bf16_t)a0.z; p2[1]=(bf16_t)a1.z;
      bf16x2 p3; p3[0]=(bf16_t)a0.w; p3[1]=(bf16_t)a1.w;
      *(bf16x2*)&Vsh[d0 + 0][vkp] = p0;
      *(bf16x2*)&Vsh[d0 + 1][vkp] = p1;
      *(bf16x2*)&Vsh[d0 + 2][vkp] = p2;
      *(bf16x2*)&Vsh[d0 + 3][vkp] = p3;
    }
    __syncthreads();

    const int kbn = kb + BN;
    if (kbn < SEQ) {
#pragma unroll
      for (int i = 0; i < 8; ++i) {
        int v = tid + i * 256, row = v >> 5, c4 = (v & 31) * 4;
        kreg[i] = *(const float4*)(Kb + (size_t)(kbn + row) * HD + c4);
      }
#pragma unroll
      for (int i = 0; i < 4; ++i) {
        int d0 = (vg + i * 8) * 4;
        const float* vp0 = Vb + (size_t)(kbn + vkp) * HD + d0;
        vreg[2 * i] = *(const float4*)vp0;
        vreg[2 * i + 1] = *(const float4*)(vp0 + HD);
      }
    }

    f32x4 s[4];
#pragma unroll
    for (int ct = 0; ct < 4; ++ct) { s[ct][0]=0.f; s[ct][1]=0.f; s[ct][2]=0.f; s[ct][3]=0.f; }
#pragma unroll
    for (int kf = 0; kf < 4; ++kf)
#pragma unroll
      for (int ct = 0; ct < 4; ++ct) {
        bf16x8 ak = *(const bf16x8*)&Ksh[ct * 16 + l15][kf * 32 + quad * 8];
        s[ct] = __builtin_amdgcn_mfma_f32_16x16x32_bf16(ak, aq[kf], s[ct], 0, 0, 0);
      }

    float mx = s[0][0];
#pragma unroll
    for (int ct = 0; ct < 4; ++ct)
#pragma unroll
      for (int r = 0; r < 4; ++r) mx = fmaxf(mx, s[ct][r]);
    mx = fmaxf(mx, __shfl_xor(mx, 16));
    mx = fmaxf(mx, __shfl_xor(mx, 32));
    float mnew = fmaxf(m_r, mx);
    float alpha = __expf(m_r - mnew);
    m_r = mnew;
    float ls = 0.f;
#pragma unroll
    for (int ct = 0; ct < 4; ++ct)
#pragma unroll
      for (int r = 0; r < 4; ++r) {
        float p = __expf(s[ct][r] - mnew);
        s[ct][r] = p; ls += p;
      }
    ls += __shfl_xor(ls, 16);
    ls += __shfl_xor(ls, 32);
    l_r = l_r * alpha + ls;

#pragma unroll
    for (int ct = 0; ct < 4; ++ct) {
      bf16x4 pp;
      pp[0]=(bf16_t)s[ct][0]; pp[1]=(bf16_t)s[ct][1];
      pp[2]=(bf16_t)s[ct][2]; pp[3]=(bf16_t)s[ct][3];
      *(bf16x4*)&Psh[wq][l15][ct * 16 + quad * 4] = pp;
    }
    asm volatile("s_waitcnt lgkmcnt(0)" ::: "memory");
    bf16x8 ap0 = *(const bf16x8*)&Psh[wq][l15][quad * 8];
    bf16x8 ap1 = *(const bf16x8*)&Psh[wq][l15][32 + quad * 8];

#pragma unroll
    for (int t = 0; t < 8; ++t) {
      o[t][0]*=alpha; o[t][1]*=alpha; o[t][2]*=alpha; o[t][3]*=alpha;
    }
#pragma unroll
    for (int t = 0; t < 8; ++t) {
      bf16x8 av0 = *(const bf16x8*)&Vsh[t * 16 + l15][quad * 8];
      o[t] = __builtin_amdgcn_mfma_f32_16x16x32_bf16(av0, ap0, o[t], 0, 0, 0);
      bf16x8 av1 = *(const bf16x8*)&Vsh[t * 16 + l15][32 + quad * 8];
      o[t] = __builtin_amdgcn_mfma_f32_16x16x32_bf16(av1, ap1, o[t], 0, 0, 0);
    }
  }

  float inv = 1.0f / l_r;
  const int qrow = wq * 16 + l15;
#pragma unroll
  for (int t = 0; t < 8; ++t) {
    float4 w;
    w.x = o[t][0]*inv; w.y = o[t][1]*inv; w.z = o[t][2]*inv; w.w = o[t][3]*inv;
    *(float4*)&Ob[(size_t)qrow * HD + t * 16 + quad * 4] = w;
  }
}

extern "C" void kernel_launch(void* const* d_in, const int* in_sizes, int n_in,
                              void* d_out, int out_size, void* d_ws, size_t ws_size,
                              hipStream_t stream) {
  const float* q = (const float*)d_in[0];
  const float* k = (const float*)d_in[1];
  const float* v = (const float*)d_in[2];
  float* out = (float*)d_out;

  const size_t elems = (size_t)NB * SEQ * HD;          // 8388608
  const size_t need = elems * 2 * 3;                   // Qs + Kb + Vt bf16 = 48 MiB

  if (ws_size >= need) {
    bf16_t* Qs = (bf16_t*)d_ws;
    bf16_t* Kb = Qs + elems;
    bf16_t* Vt = Kb + elems;
    prep_kernel<<<6144, 256, 0, stream>>>(q, k, v, Qs, Kb, Vt);
    fa13_kernel<<<NB * (SEQ / 128), 512, 0, stream>>>(Qs, Kb, Vt, out);
  } else {
    fa_fallback<<<NB * (SEQ / BM), 256, 0, stream>>>(q, k, v, out);
  }
}

// Round 9
// 232.293 us; speedup vs baseline: 1.1631x; 1.1631x over previous
//
#include <hip/hip_runtime.h>
#include <math.h>
#include <stdint.h>

typedef __bf16 bf16_t;
typedef __bf16 bf16x2 __attribute__((ext_vector_type(2)));
typedef __bf16 bf16x4 __attribute__((ext_vector_type(4)));
typedef __bf16 bf16x8 __attribute__((ext_vector_type(8)));
typedef float f32x4 __attribute__((ext_vector_type(4)));
typedef float f32x16 __attribute__((ext_vector_type(16)));

#define NB   32
#define SEQ  2048
#define HD   128
#define SCALE 0.08838834764831845f
#define LOG2E 1.4426950408889634f

__device__ __forceinline__ float fast_exp2(float x) {
#if __has_builtin(__builtin_amdgcn_exp2f)
  return __builtin_amdgcn_exp2f(x);
#else
  return exp2f(x);
#endif
}

// ============================ prep kernel =================================
// blocks 0..2047:    Qs = bf16(Q * SCALE * LOG2E)   (exp2-unit scores)
// blocks 2048..4095: Kb = bf16(K)
// blocks 4096..6143: Vt = bf16(V) transposed [B][D][S], conflict-free f32 tile
__global__ __launch_bounds__(256) void prep_kernel(
    const float* __restrict__ Q, const float* __restrict__ K,
    const float* __restrict__ V, bf16_t* __restrict__ Qs,
    bf16_t* __restrict__ Kb, bf16_t* __restrict__ Vt)
{
  const int b = blockIdx.x;
  const int tid = threadIdx.x;
  if (b < 4096) {
    const bool isQ = (b < 2048);
    const float* src = isQ ? Q : K;
    bf16_t* dst = isQ ? Qs : Kb;
    const float sc = isQ ? (SCALE * LOG2E) : 1.0f;
    size_t base4 = (size_t)(isQ ? b : b - 2048) * 1024;
#pragma unroll
    for (int i = 0; i < 4; ++i) {
      size_t idx = base4 + tid + i * 256;
      float4 x = ((const float4*)src)[idx];
      bf16x4 y;
      y[0] = (bf16_t)(x.x * sc); y[1] = (bf16_t)(x.y * sc);
      y[2] = (bf16_t)(x.z * sc); y[3] = (bf16_t)(x.w * sc);
      ((bf16x4*)dst)[idx] = y;
    }
  } else {
    // f32 tile, stride 65: bank(s,d) = (s + d) % 32 -> conflict-free both sides.
    __shared__ float tile[64][65];  // 16.6 KB
    const int bt = b - 4096;
    const int batch = bt >> 6;
    const int rem = bt & 63;
    const int s0 = (rem >> 1) * 64;
    const int d0 = (rem & 1) * 64;
#pragma unroll
    for (int i = 0; i < 4; ++i) {
      int e = tid + i * 256;
      int s = e >> 4, dq = e & 15;
      float4 x = *(const float4*)&V[((size_t)batch * SEQ + s0 + s) * HD + d0 + dq * 4];
      tile[s][dq * 4 + 0] = x.x;
      tile[s][dq * 4 + 1] = x.y;
      tile[s][dq * 4 + 2] = x.z;
      tile[s][dq * 4 + 3] = x.w;
    }
    __syncthreads();
#pragma unroll
    for (int i = 0; i < 2; ++i) {
      int g = tid + i * 256;
      int d = g >> 3, sg = g & 7;
      bf16x8 w;
#pragma unroll
      for (int j = 0; j < 8; ++j) w[j] = (bf16_t)tile[sg * 8 + j][d];
      *(bf16x8*)&Vt[((size_t)batch * HD + d0 + d) * SEQ + s0 + sg * 8] = w;
    }
  }
}

// ============================ main kernel =================================
// fa14 = fa12 (proven 122.5us: 32x32x16, split-K pairs, in-register P via
// 4x shfl_xor) + T15 lagged PV + XCD swizzle:
//   - at iter t: QK(t) MFMAs, then PV(t-1) MFMAs (bp registers from t-1,
//     V(t-1) in a triple-buffered LDS slot).  The 8 PV MFMAs bridge the
//     QK->softmax dependency gap; on the defer-max common path nothing
//     reads o until next iter, so PV completion is fully hidden.
//   - algebra bit-identical: o <- (o + P(t-1)V(t-1)) * alpha_t is the same
//     term grouping as fa12's recurrence.
//   - LDS = K 2x16KB + V 3x16KB = 80KB exactly -> still 2 blocks/CU;
//     epilogue scratch aliases the same memory after a barrier.
//   - bijective XCD swizzle (grid 1024 = 8*128): each XCD's L2 covers 4
//     batches of KV.
__global__ __launch_bounds__(256) void fa14_kernel(
    const bf16_t* __restrict__ Qs, const bf16_t* __restrict__ Kbf,
    const bf16_t* __restrict__ Vt, float* __restrict__ O)
{
  __shared__ __attribute__((aligned(16))) char smem[81920];  // 80 KB exactly
  bf16_t* const Ksw = (bf16_t*)smem;               // 2 x 8192 bf16 (32 KB)
  bf16_t* const Vsw = (bf16_t*)(smem + 32768);     // 3 x 8192 bf16 (48 KB)

  const int tid  = threadIdx.x;
  const int lane = tid & 63;
  const int wq   = tid >> 6;
  const int hi   = lane >> 5;        // half of wave
  const int q31  = lane & 31;        // q-column within 32-row q-group
  const int pair = wq >> 1;          // 0: q 0-31, 1: q 32-63
  const int sub  = wq & 1;           // k-half within pair
  const int koff = sub * 32;

  // bijective XCD swizzle: 1024 blocks -> XCD x gets logical [x*128, x*128+128)
  const int L     = ((blockIdx.x & 7) << 7) | (blockIdx.x >> 3);
  const int batch = L >> 5;
  const int qt    = L & 31;

  const bf16_t* Qb = Qs + ((size_t)batch * SEQ + qt * 64 + pair * 32) * HD;
  const bf16_t* Kb = Kbf + (size_t)batch * SEQ * HD;
  const bf16_t* Vb = Vt + (size_t)batch * HD * SEQ;
  float*        Ob = O + ((size_t)batch * SEQ + qt * 64) * HD;

  // ---- Q fragments (B-operand): B[col=q31][k=d = dc*16 + hi*8 + j] ----
  bf16x8 bq[8];
#pragma unroll
  for (int dc = 0; dc < 8; ++dc)
    bq[dc] = *(const bf16x8*)&Qb[(size_t)q31 * HD + dc * 16 + hi * 8];

  f32x16 o[4];
#pragma unroll
  for (int dt = 0; dt < 4; ++dt)
#pragma unroll
    for (int r = 0; r < 16; ++r) o[dt][r] = 0.f;
  float m_r = -INFINITY, l_r = 0.0f;

  // P fragments of previous tile (PV B-operands), carried across iterations
  bf16x8 bp0p, bp1p;

  // ---- DMA staging: wave stages 16 K-rows + 32 V-rows per tile ----
  auto stage = [&](int kbuf, int vbuf, int kb) {
#pragma unroll
    for (int i = 0; i < 4; ++i) {
      int row = wq * 16 + i * 4 + (lane >> 4);
      int gk = (lane & 15) ^ (row & 15);
      const bf16_t* gp = Kb + (size_t)(kb + row) * HD + gk * 8;
      __builtin_amdgcn_global_load_lds(
          (const __attribute__((address_space(1))) void*)gp,
          (__attribute__((address_space(3))) void*)&Ksw[kbuf * 8192 + (wq * 16 + i * 4) * 128],
          16, 0, 0);
    }
#pragma unroll
    for (int i = 0; i < 4; ++i) {
      int d = wq * 32 + i * 8 + (lane >> 3);
      int gv = (lane & 7) ^ (d & 7);
      const bf16_t* gp = Vb + (size_t)d * SEQ + kb + gv * 8;
      __builtin_amdgcn_global_load_lds(
          (const __attribute__((address_space(1))) void*)gp,
          (__attribute__((address_space(3))) void*)&Vsw[vbuf * 8192 + (wq * 32 + i * 8) * 64],
          16, 0, 0);
    }
  };

  stage(0, 0, 0);   // tile 0: K buf 0, V buf 0

  for (int t = 0; t < SEQ / 64; ++t) {
    __syncthreads();  // drains own DMA + all prior LDS reads (protects rotation)
    const int vnext = (t + 1) % 3;
    const int vprev = (t + 2) % 3;   // == (t-1) mod 3
    if (t + 1 < SEQ / 64) stage((t + 1) & 1, vnext, (t + 1) * 64);

    const bf16_t* Ks = &Ksw[(t & 1) * 8192];

    // ---- S^T = K Q^T on this wave's 32-k half (log2 units) ----
    f32x16 s;
#pragma unroll
    for (int r = 0; r < 16; ++r) s[r] = 0.f;
    {
      const int row = koff + q31;
      const int rsw = row & 15;
#pragma unroll
      for (int dc = 0; dc < 8; ++dc) {
        bf16x8 ak = *(const bf16x8*)&Ks[row * 128 + (((dc * 2 + hi) ^ rsw) * 8)];
        s = __builtin_amdgcn_mfma_f32_32x32x16_bf16(ak, bq[dc], s, 0, 0, 0);
      }
    }

    // ---- lagged PV(t-1): independent of s; fills the QK->softmax gap ----
    if (t > 0) {
      const bf16_t* Vp = &Vsw[vprev * 8192];
      const int g0 = (koff >> 3) + hi;
      const int g1 = g0 + 2;
#pragma unroll
      for (int dt = 0; dt < 4; ++dt) {
        const int d = dt * 32 + q31;
        const int dsw = d & 7;
        bf16x8 av0 = *(const bf16x8*)&Vp[d * 64 + ((g0 ^ dsw) * 8)];
        o[dt] = __builtin_amdgcn_mfma_f32_32x32x16_bf16(av0, bp0p, o[dt], 0, 0, 0);
        bf16x8 av1 = *(const bf16x8*)&Vp[d * 64 + ((g1 ^ dsw) * 8)];
        o[dt] = __builtin_amdgcn_mfma_f32_32x32x16_bf16(av1, bp1p, o[dt], 0, 0, 0);
      }
    }

    // ---- softmax: row max across this wave's 32 k ----
    float mx = s[0];
#pragma unroll
    for (int r = 1; r < 16; ++r) mx = fmaxf(mx, s[r]);
    mx = fmaxf(mx, __shfl_xor(mx, 32));

    // ---- defer-max: rescale only when max grew by > 8 (P bounded by 256) ----
    if (!__all(mx <= m_r + 8.0f)) {
      const float mnew = fmaxf(m_r, mx);
      const float alpha = fast_exp2(m_r - mnew);
      m_r = mnew;
      l_r *= alpha;
#pragma unroll
      for (int dt = 0; dt < 4; ++dt) o[dt] = o[dt] * alpha;
    }

    // ---- P = exp2(S - m), partial row sum ----
    float ls = 0.f;
#pragma unroll
    for (int r = 0; r < 16; ++r) {
      float p = fast_exp2(s[r] - m_r);
      s[r] = p; ls += p;
    }
    ls += __shfl_xor(ls, 32);
    l_r += ls;

    // ---- pack P to bf16 pairs; assemble PV B-fragments via 4 shfl_xor ----
    uint32_t pk[8];
#pragma unroll
    for (int i = 0; i < 8; ++i) {
      union { bf16x2 v; uint32_t u; } c;
      c.v[0] = (bf16_t)s[2 * i];
      c.v[1] = (bf16_t)s[2 * i + 1];
      pk[i] = c.u;
    }
    uint32_t t0 = __shfl_xor((int)(hi ? pk[0] : pk[2]), 32);
    uint32_t t1 = __shfl_xor((int)(hi ? pk[1] : pk[3]), 32);
    uint32_t t2 = __shfl_xor((int)(hi ? pk[4] : pk[6]), 32);
    uint32_t t3 = __shfl_xor((int)(hi ? pk[5] : pk[7]), 32);
    {
      union { bf16x8 v; uint32_t w[4]; } B;
      if (hi) { B.w[0] = t0; B.w[1] = t1; B.w[2] = pk[2]; B.w[3] = pk[3]; }
      else    { B.w[0] = pk[0]; B.w[1] = pk[1]; B.w[2] = t0; B.w[3] = t1; }
      bp0p = B.v;
      if (hi) { B.w[0] = t2; B.w[1] = t3; B.w[2] = pk[6]; B.w[3] = pk[7]; }
      else    { B.w[0] = pk[4]; B.w[1] = pk[5]; B.w[2] = t2; B.w[3] = t3; }
      bp1p = B.v;
    }
  }

  // ---- final PV(T-1): V in buffer (T-1)%3, staged at iter T-2, drained ----
  {
    const bf16_t* Vp = &Vsw[((SEQ / 64 - 1) % 3) * 8192];
    const int g0 = (koff >> 3) + hi;
    const int g1 = g0 + 2;
#pragma unroll
    for (int dt = 0; dt < 4; ++dt) {
      const int d = dt * 32 + q31;
      const int dsw = d & 7;
      bf16x8 av0 = *(const bf16x8*)&Vp[d * 64 + ((g0 ^ dsw) * 8)];
      o[dt] = __builtin_amdgcn_mfma_f32_32x32x16_bf16(av0, bp0p, o[dt], 0, 0, 0);
      bf16x8 av1 = *(const bf16x8*)&Vp[d * 64 + ((g1 ^ dsw) * 8)];
      o[dt] = __builtin_amdgcn_mfma_f32_32x32x16_bf16(av1, bp1p, o[dt], 0, 0, 0);
    }
  }

  // ================= epilogue: merge k-halves, store =================
  __syncthreads();  // all loop/final-PV LDS reads done; alias smem as scratch
  float* const sf  = (float*)smem;              // pair*4224 + q*132 + d
  float* const mlb = (float*)(smem + 33792);    // 2 pairs x {m[32], l[32]}

  if (sub == 1) {
    if (hi == 0) {
      mlb[pair * 64 + q31]      = m_r;
      mlb[pair * 64 + 32 + q31] = l_r;
    }
#pragma unroll
    for (int dt = 0; dt < 4; ++dt)
#pragma unroll
      for (int r = 0; r < 16; ++r) {
        int d = dt * 32 + (r & 3) + 8 * (r >> 2) + 4 * hi;
        sf[pair * 4224 + q31 * 132 + d] = o[dt][r];
      }
  }
  __syncthreads();
  if (sub == 0) {
    float m1 = mlb[pair * 64 + q31];
    float l1 = mlb[pair * 64 + 32 + q31];
    float m = fmaxf(m_r, m1);
    float e0 = fast_exp2(m_r - m);
    float e1 = fast_exp2(m1 - m);
    float inv = 1.0f / (l_r * e0 + l1 * e1);
    float f0 = e0 * inv, f1 = e1 * inv;
#pragma unroll
    for (int dt = 0; dt < 4; ++dt)
#pragma unroll
      for (int r = 0; r < 16; ++r) {
        int d = dt * 32 + (r & 3) + 8 * (r >> 2) + 4 * hi;
        float* p = &sf[pair * 4224 + q31 * 132 + d];
        *p = o[dt][r] * f0 + *p * f1;
      }
  }
  __syncthreads();
  // cooperative coalesced store: 128 threads per pair, 8 float4 each
  {
    const int tid2 = sub * 64 + lane;   // 0..127 within pair
#pragma unroll
    for (int i = 0; i < 8; ++i) {
      int idx = tid2 + i * 128;         // 0..1023
      int q = idx >> 5;
      int dg = idx & 31;
      float4 v = *(const float4*)&sf[pair * 4224 + q * 132 + dg * 4];
      *(float4*)&Ob[(size_t)(pair * 32 + q) * HD + dg * 4] = v;
    }
  }
}

// ===================== fallback (proven R2 kernel) ========================
#define BM   64
#define BN   64
#define KPAD 8
#define VPAD 8
#define PPAD 8

__global__ __launch_bounds__(256) void fa_fallback(
    const float* __restrict__ Q, const float* __restrict__ K,
    const float* __restrict__ V, float* __restrict__ O)
{
  __shared__ __attribute__((aligned(16))) bf16_t Ksh[BN][HD + KPAD];
  __shared__ __attribute__((aligned(16))) bf16_t Vsh[HD][BN + VPAD];
  __shared__ __attribute__((aligned(16))) bf16_t Psh[4][16][BN + PPAD];

  const int tid = threadIdx.x;
  const int lane = tid & 63;
  const int wq = tid >> 6;
  const int quad = lane >> 4;
  const int l15 = lane & 15;
  const int bid = blockIdx.x;
  const int batch = bid >> 5;
  const int qt = bid & 31;

  const float* Qb = Q + (size_t)batch * SEQ * HD + (size_t)qt * BM * HD;
  const float* Kb = K + (size_t)batch * SEQ * HD;
  const float* Vb = V + (size_t)batch * SEQ * HD;
  float* Ob = O + (size_t)batch * SEQ * HD + (size_t)qt * BM * HD;

  bf16x8 aq[4];
  {
    const int qrow = wq * 16 + l15;
#pragma unroll
    for (int kf = 0; kf < 4; ++kf) {
      const float* qp = Qb + (size_t)qrow * HD + kf * 32 + quad * 8;
      float4 x0 = *(const float4*)(qp);
      float4 x1 = *(const float4*)(qp + 4);
      bf16x8 a;
      a[0] = (bf16_t)(x0.x * SCALE); a[1] = (bf16_t)(x0.y * SCALE);
      a[2] = (bf16_t)(x0.z * SCALE); a[3] = (bf16_t)(x0.w * SCALE);
      a[4] = (bf16_t)(x1.x * SCALE); a[5] = (bf16_t)(x1.y * SCALE);
      a[6] = (bf16_t)(x1.z * SCALE); a[7] = (bf16_t)(x1.w * SCALE);
      aq[kf] = a;
    }
  }

  f32x4 o[8];
#pragma unroll
  for (int t = 0; t < 8; ++t) { o[t][0]=0.f; o[t][1]=0.f; o[t][2]=0.f; o[t][3]=0.f; }
  float m_r = -INFINITY, l_r = 0.0f;
  const int vkp = (tid & 31) * 2;
  const int vg = tid >> 5;
  float4 kreg[8], vreg[8];

#pragma unroll
  for (int i = 0; i < 8; ++i) {
    int v = tid + i * 256, row = v >> 5, c4 = (v & 31) * 4;
    kreg[i] = *(const float4*)(Kb + (size_t)row * HD + c4);
  }
#pragma unroll
  for (int i = 0; i < 4; ++i) {
    int d0 = (vg + i * 8) * 4;
    const float* vp0 = Vb + (size_t)vkp * HD + d0;
    vreg[2 * i] = *(const float4*)vp0;
    vreg[2 * i + 1] = *(const float4*)(vp0 + HD);
  }

  for (int kb = 0; kb < SEQ; kb += BN) {
    __syncthreads();
#pragma unroll
    for (int i = 0; i < 8; ++i) {
      int v = tid + i * 256, row = v >> 5, c4 = (v & 31) * 4;
      float4 kv = kreg[i];
      bf16x4 kk;
      kk[0]=(bf16_t)kv.x; kk[1]=(bf16_t)kv.y; kk[2]=(bf16_t)kv.z; kk[3]=(bf16_t)kv.w;
      *(bf16x4*)&Ksh[row][c4] = kk;
    }
#pragma unroll
    for (int i = 0; i < 4; ++i) {
      int d0 = (vg + i * 8) * 4;
      float4 a0 = vreg[2 * i], a1 = vreg[2 * i + 1];
      bf16x2 p0; p0[0]=(bf16_t)a0.x; p0[1]=(bf16_t)a1.x;
      bf16x2 p1; p1[0]=(bf16_t)a0.y; p1[1]=(bf16_t)a1.y;
      bf16x2 p2; p2[0]=(bf16_t)a0.z; p2[1]=(bf16_t)a1.z;
      bf16x2 p3; p3[0]=(bf16_t)a0.w; p3[1]=(bf16_t)a1.w;
      *(bf16x2*)&Vsh[d0 + 0][vkp] = p0;
      *(bf16x2*)&Vsh[d0 + 1][vkp] = p1;
      *(bf16x2*)&Vsh[d0 + 2][vkp] = p2;
      *(bf16x2*)&Vsh[d0 + 3][vkp] = p3;
    }
    __syncthreads();

    const int kbn = kb + BN;
    if (kbn < SEQ) {
#pragma unroll
      for (int i = 0; i < 8; ++i) {
        int v = tid + i * 256, row = v >> 5, c4 = (v & 31) * 4;
        kreg[i] = *(const float4*)(Kb + (size_t)(kbn + row) * HD + c4);
      }
#pragma unroll
      for (int i = 0; i < 4; ++i) {
        int d0 = (vg + i * 8) * 4;
        const float* vp0 = Vb + (size_t)(kbn + vkp) * HD + d0;
        vreg[2 * i] = *(const float4*)vp0;
        vreg[2 * i + 1] = *(const float4*)(vp0 + HD);
      }
    }

    f32x4 s[4];
#pragma unroll
    for (int ct = 0; ct < 4; ++ct) { s[ct][0]=0.f; s[ct][1]=0.f; s[ct][2]=0.f; s[ct][3]=0.f; }
#pragma unroll
    for (int kf = 0; kf < 4; ++kf)
#pragma unroll
      for (int ct = 0; ct < 4; ++ct) {
        bf16x8 ak = *(const bf16x8*)&Ksh[ct * 16 + l15][kf * 32 + quad * 8];
        s[ct] = __builtin_amdgcn_mfma_f32_16x16x32_bf16(ak, aq[kf], s[ct], 0, 0, 0);
      }

    float mx = s[0][0];
#pragma unroll
    for (int ct = 0; ct < 4; ++ct)
#pragma unroll
      for (int r = 0; r < 4; ++r) mx = fmaxf(mx, s[ct][r]);
    mx = fmaxf(mx, __shfl_xor(mx, 16));
    mx = fmaxf(mx, __shfl_xor(mx, 32));
    float mnew = fmaxf(m_r, mx);
    float alpha = __expf(m_r - mnew);
    m_r = mnew;
    float ls = 0.f;
#pragma unroll
    for (int ct = 0; ct < 4; ++ct)
#pragma unroll
      for (int r = 0; r < 4; ++r) {
        float p = __expf(s[ct][r] - mnew);
        s[ct][r] = p; ls += p;
      }
    ls += __shfl_xor(ls, 16);
    ls += __shfl_xor(ls, 32);
    l_r = l_r * alpha + ls;

#pragma unroll
    for (int ct = 0; ct < 4; ++ct) {
      bf16x4 pp;
      pp[0]=(bf16_t)s[ct][0]; pp[1]=(bf16_t)s[ct][1];
      pp[2]=(bf16_t)s[ct][2]; pp[3]=(bf16_t)s[ct][3];
      *(bf16x4*)&Psh[wq][l15][ct * 16 + quad * 4] = pp;
    }
    asm volatile("s_waitcnt lgkmcnt(0)" ::: "memory");
    bf16x8 ap0 = *(const bf16x8*)&Psh[wq][l15][quad * 8];
    bf16x8 ap1 = *(const bf16x8*)&Psh[wq][l15][32 + quad * 8];

#pragma unroll
    for (int t = 0; t < 8; ++t) {
      o[t][0]*=alpha; o[t][1]*=alpha; o[t][2]*=alpha; o[t][3]*=alpha;
    }
#pragma unroll
    for (int t = 0; t < 8; ++t) {
      bf16x8 av0 = *(const bf16x8*)&Vsh[t * 16 + l15][quad * 8];
      o[t] = __builtin_amdgcn_mfma_f32_16x16x32_bf16(av0, ap0, o[t], 0, 0, 0);
      bf16x8 av1 = *(const bf16x8*)&Vsh[t * 16 + l15][32 + quad * 8];
      o[t] = __builtin_amdgcn_mfma_f32_16x16x32_bf16(av1, ap1, o[t], 0, 0, 0);
    }
  }

  float inv = 1.0f / l_r;
  const int qrow = wq * 16 + l15;
#pragma unroll
  for (int t = 0; t < 8; ++t) {
    float4 w;
    w.x = o[t][0]*inv; w.y = o[t][1]*inv; w.z = o[t][2]*inv; w.w = o[t][3]*inv;
    *(float4*)&Ob[(size_t)qrow * HD + t * 16 + quad * 4] = w;
  }
}

extern "C" void kernel_launch(void* const* d_in, const int* in_sizes, int n_in,
                              void* d_out, int out_size, void* d_ws, size_t ws_size,
                              hipStream_t stream) {
  const float* q = (const float*)d_in[0];
  const float* k = (const float*)d_in[1];
  const float* v = (const float*)d_in[2];
  float* out = (float*)d_out;

  const size_t elems = (size_t)NB * SEQ * HD;          // 8388608
  const size_t need = elems * 2 * 3;                   // Qs + Kb + Vt bf16 = 48 MiB

  if (ws_size >= need) {
    bf16_t* Qs = (bf16_t*)d_ws;
    bf16_t* Kb = Qs + elems;
    bf16_t* Vt = Kb + elems;
    prep_kernel<<<6144, 256, 0, stream>>>(q, k, v, Qs, Kb, Vt);
    fa14_kernel<<<NB * (SEQ / 64), 256, 0, stream>>>(Qs, Kb, Vt, out);
  } else {
    fa_fallback<<<NB * (SEQ / BM), 256, 0, stream>>>(q, k, v, out);
  }
}

// Round 10
// 225.023 us; speedup vs baseline: 1.2007x; 1.0323x over previous
//
#include <hip/hip_runtime.h>
#include <math.h>
#include <stdint.h>

typedef __bf16 bf16_t;
typedef __bf16 bf16x2 __attribute__((ext_vector_type(2)));
typedef __bf16 bf16x4 __attribute__((ext_vector_type(4)));
typedef __bf16 bf16x8 __attribute__((ext_vector_type(8)));
typedef float f32x4 __attribute__((ext_vector_type(4)));
typedef float f32x16 __attribute__((ext_vector_type(16)));

#define NB   32
#define SEQ  2048
#define HD   128
#define SCALE 0.08838834764831845f
#define LOG2E 1.4426950408889634f

__device__ __forceinline__ float fast_exp2(float x) {
#if __has_builtin(__builtin_amdgcn_exp2f)
  return __builtin_amdgcn_exp2f(x);
#else
  return exp2f(x);
#endif
}

// ============================ prep kernel =================================
// blocks 0..2047:    Kb = bf16(K)                 (Q converted inline in fa15)
// blocks 2048..4095: Vt = bf16(V) transposed [B][D][S], conflict-free f32 tile
__global__ __launch_bounds__(256) void prep_kernel(
    const float* __restrict__ K, const float* __restrict__ V,
    bf16_t* __restrict__ Kb, bf16_t* __restrict__ Vt)
{
  const int b = blockIdx.x;
  const int tid = threadIdx.x;
  if (b < 2048) {
    size_t base4 = (size_t)b * 1024;
#pragma unroll
    for (int i = 0; i < 4; ++i) {
      size_t idx = base4 + tid + i * 256;
      float4 x = ((const float4*)K)[idx];
      bf16x4 y;
      y[0] = (bf16_t)x.x; y[1] = (bf16_t)x.y;
      y[2] = (bf16_t)x.z; y[3] = (bf16_t)x.w;
      ((bf16x4*)Kb)[idx] = y;
    }
  } else {
    // f32 tile, stride 65: bank(s,d) = (s + d) % 32 -> conflict-free both sides.
    __shared__ float tile[64][65];  // 16.6 KB
    const int bt = b - 2048;
    const int batch = bt >> 6;
    const int rem = bt & 63;
    const int s0 = (rem >> 1) * 64;
    const int d0 = (rem & 1) * 64;
#pragma unroll
    for (int i = 0; i < 4; ++i) {
      int e = tid + i * 256;
      int s = e >> 4, dq = e & 15;
      float4 x = *(const float4*)&V[((size_t)batch * SEQ + s0 + s) * HD + d0 + dq * 4];
      tile[s][dq * 4 + 0] = x.x;
      tile[s][dq * 4 + 1] = x.y;
      tile[s][dq * 4 + 2] = x.z;
      tile[s][dq * 4 + 3] = x.w;
    }
    __syncthreads();
#pragma unroll
    for (int i = 0; i < 2; ++i) {
      int g = tid + i * 256;
      int d = g >> 3, sg = g & 7;
      bf16x8 w;
#pragma unroll
      for (int j = 0; j < 8; ++j) w[j] = (bf16_t)tile[sg * 8 + j][d];
      *(bf16x8*)&Vt[((size_t)batch * HD + d0 + d) * SEQ + s0 + sg * 8] = w;
    }
  }
}

// ============================ main kernel =================================
// fa15 = fa14 (proven 113.3us: 32x32x16, split-K pairs, in-register P,
// lagged PV, triple-buffered V, XCD swizzle) + three proven-safe increments:
//   (a) Q read inline from fp32 (SCALE*LOG2E folded) -> prep drops its Q
//       pass (144->96 MB prep traffic).  Same bf16 values -> absmax same.
//   (b) s_setprio(1) around the QK + lagged-PV MFMA cluster (m191 regime:
//       2 independent blocks/CU with QK/PV/softmax phase diversity).
//   (c) tree row-max (max3-fusable, depth 4); fmax is exactly associative
//       and l-summation order is fa14-identical -> bit-identical output.
__global__ __launch_bounds__(256) void fa15_kernel(
    const float* __restrict__ Q, const bf16_t* __restrict__ Kbf,
    const bf16_t* __restrict__ Vt, float* __restrict__ O)
{
  __shared__ __attribute__((aligned(16))) char smem[81920];  // 80 KB exactly
  bf16_t* const Ksw = (bf16_t*)smem;               // 2 x 8192 bf16 (32 KB)
  bf16_t* const Vsw = (bf16_t*)(smem + 32768);     // 3 x 8192 bf16 (48 KB)

  const int tid  = threadIdx.x;
  const int lane = tid & 63;
  const int wq   = tid >> 6;
  const int hi   = lane >> 5;        // half of wave
  const int q31  = lane & 31;        // q-column within 32-row q-group
  const int pair = wq >> 1;          // 0: q 0-31, 1: q 32-63
  const int sub  = wq & 1;           // k-half within pair
  const int koff = sub * 32;

  // bijective XCD swizzle: 1024 blocks -> XCD x gets logical [x*128, x*128+128)
  const int L     = ((blockIdx.x & 7) << 7) | (blockIdx.x >> 3);
  const int batch = L >> 5;
  const int qt    = L & 31;

  const float*  Qb = Q   + ((size_t)batch * SEQ + qt * 64 + pair * 32) * HD;
  const bf16_t* Kb = Kbf + (size_t)batch * SEQ * HD;
  const bf16_t* Vb = Vt  + (size_t)batch * HD * SEQ;
  float*        Ob = O   + ((size_t)batch * SEQ + qt * 64) * HD;

  // ---- Q fragments from fp32, SCALE*LOG2E folded (B-operand):
  //      B[col=q31][k=d = dc*16 + hi*8 + j] ----
  bf16x8 bq[8];
  {
    const float qs = SCALE * LOG2E;
#pragma unroll
    for (int dc = 0; dc < 8; ++dc) {
      const float* qp = Qb + (size_t)q31 * HD + dc * 16 + hi * 8;
      float4 x0 = *(const float4*)qp;
      float4 x1 = *(const float4*)(qp + 4);
      bf16x8 a;
      a[0] = (bf16_t)(x0.x * qs); a[1] = (bf16_t)(x0.y * qs);
      a[2] = (bf16_t)(x0.z * qs); a[3] = (bf16_t)(x0.w * qs);
      a[4] = (bf16_t)(x1.x * qs); a[5] = (bf16_t)(x1.y * qs);
      a[6] = (bf16_t)(x1.z * qs); a[7] = (bf16_t)(x1.w * qs);
      bq[dc] = a;
    }
  }

  f32x16 o[4];
#pragma unroll
  for (int dt = 0; dt < 4; ++dt)
#pragma unroll
    for (int r = 0; r < 16; ++r) o[dt][r] = 0.f;
  float m_r = -INFINITY, l_r = 0.0f;

  // P fragments of previous tile (PV B-operands), carried across iterations
  bf16x8 bp0p, bp1p;

  // ---- DMA staging: wave stages 16 K-rows + 32 V-rows per tile ----
  auto stage = [&](int kbuf, int vbuf, int kb) {
#pragma unroll
    for (int i = 0; i < 4; ++i) {
      int row = wq * 16 + i * 4 + (lane >> 4);
      int gk = (lane & 15) ^ (row & 15);
      const bf16_t* gp = Kb + (size_t)(kb + row) * HD + gk * 8;
      __builtin_amdgcn_global_load_lds(
          (const __attribute__((address_space(1))) void*)gp,
          (__attribute__((address_space(3))) void*)&Ksw[kbuf * 8192 + (wq * 16 + i * 4) * 128],
          16, 0, 0);
    }
#pragma unroll
    for (int i = 0; i < 4; ++i) {
      int d = wq * 32 + i * 8 + (lane >> 3);
      int gv = (lane & 7) ^ (d & 7);
      const bf16_t* gp = Vb + (size_t)d * SEQ + kb + gv * 8;
      __builtin_amdgcn_global_load_lds(
          (const __attribute__((address_space(1))) void*)gp,
          (__attribute__((address_space(3))) void*)&Vsw[vbuf * 8192 + (wq * 32 + i * 8) * 64],
          16, 0, 0);
    }
  };

  stage(0, 0, 0);   // tile 0: K buf 0, V buf 0

  for (int t = 0; t < SEQ / 64; ++t) {
    __syncthreads();  // drains own DMA + all prior LDS reads (protects rotation)
    const int vnext = (t + 1) % 3;
    const int vprev = (t + 2) % 3;   // == (t-1) mod 3
    if (t + 1 < SEQ / 64) stage((t + 1) & 1, vnext, (t + 1) * 64);

    const bf16_t* Ks = &Ksw[(t & 1) * 8192];

    // ---- MFMA cluster: QK(t) then lagged PV(t-1), under raised priority ----
    __builtin_amdgcn_s_setprio(1);

    // S^T = K Q^T on this wave's 32-k half (log2 units)
    f32x16 s;
#pragma unroll
    for (int r = 0; r < 16; ++r) s[r] = 0.f;
    {
      const int row = koff + q31;
      const int rsw = row & 15;
#pragma unroll
      for (int dc = 0; dc < 8; ++dc) {
        bf16x8 ak = *(const bf16x8*)&Ks[row * 128 + (((dc * 2 + hi) ^ rsw) * 8)];
        s = __builtin_amdgcn_mfma_f32_32x32x16_bf16(ak, bq[dc], s, 0, 0, 0);
      }
    }

    // lagged PV(t-1): independent of s; fills the QK->softmax gap
    if (t > 0) {
      const bf16_t* Vp = &Vsw[vprev * 8192];
      const int g0 = (koff >> 3) + hi;
      const int g1 = g0 + 2;
#pragma unroll
      for (int dt = 0; dt < 4; ++dt) {
        const int d = dt * 32 + q31;
        const int dsw = d & 7;
        bf16x8 av0 = *(const bf16x8*)&Vp[d * 64 + ((g0 ^ dsw) * 8)];
        o[dt] = __builtin_amdgcn_mfma_f32_32x32x16_bf16(av0, bp0p, o[dt], 0, 0, 0);
        bf16x8 av1 = *(const bf16x8*)&Vp[d * 64 + ((g1 ^ dsw) * 8)];
        o[dt] = __builtin_amdgcn_mfma_f32_32x32x16_bf16(av1, bp1p, o[dt], 0, 0, 0);
      }
    }
    __builtin_amdgcn_s_setprio(0);

    // ---- softmax: tree row max across this wave's 32 k (max3-fusable) ----
    float ma = fmaxf(fmaxf(s[0],  s[1]),  fmaxf(s[2],  s[3]));
    float mb = fmaxf(fmaxf(s[4],  s[5]),  fmaxf(s[6],  s[7]));
    float mc = fmaxf(fmaxf(s[8],  s[9]),  fmaxf(s[10], s[11]));
    float md = fmaxf(fmaxf(s[12], s[13]), fmaxf(s[14], s[15]));
    float mx = fmaxf(fmaxf(ma, mb), fmaxf(mc, md));
    mx = fmaxf(mx, __shfl_xor(mx, 32));

    // ---- defer-max: rescale only when max grew by > 8 (P bounded by 256) ----
    if (!__all(mx <= m_r + 8.0f)) {
      const float mnew = fmaxf(m_r, mx);
      const float alpha = fast_exp2(m_r - mnew);
      m_r = mnew;
      l_r *= alpha;
#pragma unroll
      for (int dt = 0; dt < 4; ++dt) o[dt] = o[dt] * alpha;
    }

    // ---- P = exp2(S - m), partial row sum (fa14-identical order) ----
    float ls = 0.f;
#pragma unroll
    for (int r = 0; r < 16; ++r) {
      float p = fast_exp2(s[r] - m_r);
      s[r] = p; ls += p;
    }
    ls += __shfl_xor(ls, 32);
    l_r += ls;

    // ---- pack P to bf16 pairs; assemble PV B-fragments via 4 shfl_xor ----
    uint32_t pk[8];
#pragma unroll
    for (int i = 0; i < 8; ++i) {
      union { bf16x2 v; uint32_t u; } c;
      c.v[0] = (bf16_t)s[2 * i];
      c.v[1] = (bf16_t)s[2 * i + 1];
      pk[i] = c.u;
    }
    uint32_t t0 = __shfl_xor((int)(hi ? pk[0] : pk[2]), 32);
    uint32_t t1 = __shfl_xor((int)(hi ? pk[1] : pk[3]), 32);
    uint32_t t2 = __shfl_xor((int)(hi ? pk[4] : pk[6]), 32);
    uint32_t t3 = __shfl_xor((int)(hi ? pk[5] : pk[7]), 32);
    {
      union { bf16x8 v; uint32_t w[4]; } B;
      if (hi) { B.w[0] = t0; B.w[1] = t1; B.w[2] = pk[2]; B.w[3] = pk[3]; }
      else    { B.w[0] = pk[0]; B.w[1] = pk[1]; B.w[2] = t0; B.w[3] = t1; }
      bp0p = B.v;
      if (hi) { B.w[0] = t2; B.w[1] = t3; B.w[2] = pk[6]; B.w[3] = pk[7]; }
      else    { B.w[0] = pk[4]; B.w[1] = pk[5]; B.w[2] = t2; B.w[3] = t3; }
      bp1p = B.v;
    }
  }

  // ---- final PV(T-1): V in buffer (T-1)%3, staged at iter T-2, drained ----
  {
    const bf16_t* Vp = &Vsw[((SEQ / 64 - 1) % 3) * 8192];
    const int g0 = (koff >> 3) + hi;
    const int g1 = g0 + 2;
    __builtin_amdgcn_s_setprio(1);
#pragma unroll
    for (int dt = 0; dt < 4; ++dt) {
      const int d = dt * 32 + q31;
      const int dsw = d & 7;
      bf16x8 av0 = *(const bf16x8*)&Vp[d * 64 + ((g0 ^ dsw) * 8)];
      o[dt] = __builtin_amdgcn_mfma_f32_32x32x16_bf16(av0, bp0p, o[dt], 0, 0, 0);
      bf16x8 av1 = *(const bf16x8*)&Vp[d * 64 + ((g1 ^ dsw) * 8)];
      o[dt] = __builtin_amdgcn_mfma_f32_32x32x16_bf16(av1, bp1p, o[dt], 0, 0, 0);
    }
    __builtin_amdgcn_s_setprio(0);
  }

  // ================= epilogue: merge k-halves, store =================
  __syncthreads();  // all loop/final-PV LDS reads done; alias smem as scratch
  float* const sf  = (float*)smem;              // pair*4224 + q*132 + d
  float* const mlb = (float*)(smem + 33792);    // 2 pairs x {m[32], l[32]}

  if (sub == 1) {
    if (hi == 0) {
      mlb[pair * 64 + q31]      = m_r;
      mlb[pair * 64 + 32 + q31] = l_r;
    }
#pragma unroll
    for (int dt = 0; dt < 4; ++dt)
#pragma unroll
      for (int r = 0; r < 16; ++r) {
        int d = dt * 32 + (r & 3) + 8 * (r >> 2) + 4 * hi;
        sf[pair * 4224 + q31 * 132 + d] = o[dt][r];
      }
  }
  __syncthreads();
  if (sub == 0) {
    float m1 = mlb[pair * 64 + q31];
    float l1 = mlb[pair * 64 + 32 + q31];
    float m = fmaxf(m_r, m1);
    float e0 = fast_exp2(m_r - m);
    float e1 = fast_exp2(m1 - m);
    float inv = 1.0f / (l_r * e0 + l1 * e1);
    float f0 = e0 * inv, f1 = e1 * inv;
#pragma unroll
    for (int dt = 0; dt < 4; ++dt)
#pragma unroll
      for (int r = 0; r < 16; ++r) {
        int d = dt * 32 + (r & 3) + 8 * (r >> 2) + 4 * hi;
        float* p = &sf[pair * 4224 + q31 * 132 + d];
        *p = o[dt][r] * f0 + *p * f1;
      }
  }
  __syncthreads();
  // cooperative coalesced store: 128 threads per pair, 8 float4 each
  {
    const int tid2 = sub * 64 + lane;   // 0..127 within pair
#pragma unroll
    for (int i = 0; i < 8; ++i) {
      int idx = tid2 + i * 128;         // 0..1023
      int q = idx >> 5;
      int dg = idx & 31;
      float4 v = *(const float4*)&sf[pair * 4224 + q * 132 + dg * 4];
      *(float4*)&Ob[(size_t)(pair * 32 + q) * HD + dg * 4] = v;
    }
  }
}

// ===================== fallback (proven R2 kernel) ========================
#define BM   64
#define BN   64
#define KPAD 8
#define VPAD 8
#define PPAD 8

__global__ __launch_bounds__(256) void fa_fallback(
    const float* __restrict__ Q, const float* __restrict__ K,
    const float* __restrict__ V, float* __restrict__ O)
{
  __shared__ __attribute__((aligned(16))) bf16_t Ksh[BN][HD + KPAD];
  __shared__ __attribute__((aligned(16))) bf16_t Vsh[HD][BN + VPAD];
  __shared__ __attribute__((aligned(16))) bf16_t Psh[4][16][BN + PPAD];

  const int tid = threadIdx.x;
  const int lane = tid & 63;
  const int wq = tid >> 6;
  const int quad = lane >> 4;
  const int l15 = lane & 15;
  const int bid = blockIdx.x;
  const int batch = bid >> 5;
  const int qt = bid & 31;

  const float* Qb = Q + (size_t)batch * SEQ * HD + (size_t)qt * BM * HD;
  const float* Kb = K + (size_t)batch * SEQ * HD;
  const float* Vb = V + (size_t)batch * SEQ * HD;
  float* Ob = O + (size_t)batch * SEQ * HD + (size_t)qt * BM * HD;

  bf16x8 aq[4];
  {
    const int qrow = wq * 16 + l15;
#pragma unroll
    for (int kf = 0; kf < 4; ++kf) {
      const float* qp = Qb + (size_t)qrow * HD + kf * 32 + quad * 8;
      float4 x0 = *(const float4*)(qp);
      float4 x1 = *(const float4*)(qp + 4);
      bf16x8 a;
      a[0] = (bf16_t)(x0.x * SCALE); a[1] = (bf16_t)(x0.y * SCALE);
      a[2] = (bf16_t)(x0.z * SCALE); a[3] = (bf16_t)(x0.w * SCALE);
      a[4] = (bf16_t)(x1.x * SCALE); a[5] = (bf16_t)(x1.y * SCALE);
      a[6] = (bf16_t)(x1.z * SCALE); a[7] = (bf16_t)(x1.w * SCALE);
      aq[kf] = a;
    }
  }

  f32x4 o[8];
#pragma unroll
  for (int t = 0; t < 8; ++t) { o[t][0]=0.f; o[t][1]=0.f; o[t][2]=0.f; o[t][3]=0.f; }
  float m_r = -INFINITY, l_r = 0.0f;
  const int vkp = (tid & 31) * 2;
  const int vg = tid >> 5;
  float4 kreg[8], vreg[8];

#pragma unroll
  for (int i = 0; i < 8; ++i) {
    int v = tid + i * 256, row = v >> 5, c4 = (v & 31) * 4;
    kreg[i] = *(const float4*)(Kb + (size_t)row * HD + c4);
  }
#pragma unroll
  for (int i = 0; i < 4; ++i) {
    int d0 = (vg + i * 8) * 4;
    const float* vp0 = Vb + (size_t)vkp * HD + d0;
    vreg[2 * i] = *(const float4*)vp0;
    vreg[2 * i + 1] = *(const float4*)(vp0 + HD);
  }

  for (int kb = 0; kb < SEQ; kb += BN) {
    __syncthreads();
#pragma unroll
    for (int i = 0; i < 8; ++i) {
      int v = tid + i * 256, row = v >> 5, c4 = (v & 31) * 4;
      float4 kv = kreg[i];
      bf16x4 kk;
      kk[0]=(bf16_t)kv.x; kk[1]=(bf16_t)kv.y; kk[2]=(bf16_t)kv.z; kk[3]=(bf16_t)kv.w;
      *(bf16x4*)&Ksh[row][c4] = kk;
    }
#pragma unroll
    for (int i = 0; i < 4; ++i) {
      int d0 = (vg + i * 8) * 4;
      float4 a0 = vreg[2 * i], a1 = vreg[2 * i + 1];
      bf16x2 p0; p0[0]=(bf16_t)a0.x; p0[1]=(bf16_t)a1.x;
      bf16x2 p1; p1[0]=(bf16_t)a0.y; p1[1]=(bf16_t)a1.y;
      bf16x2 p2; p2[0]=(bf16_t)a0.z; p2[1]=(bf16_t)a1.z;
      bf16x2 p3; p3[0]=(bf16_t)a0.w; p3[1]=(bf16_t)a1.w;
      *(bf16x2*)&Vsh[d0 + 0][vkp] = p0;
      *(bf16x2*)&Vsh[d0 + 1][vkp] = p1;
      *(bf16x2*)&Vsh[d0 + 2][vkp] = p2;
      *(bf16x2*)&Vsh[d0 + 3][vkp] = p3;
    }
    __syncthreads();

    const int kbn = kb + BN;
    if (kbn < SEQ) {
#pragma unroll
      for (int i = 0; i < 8; ++i) {
        int v = tid + i * 256, row = v >> 5, c4 = (v & 31) * 4;
        kreg[i] = *(const float4*)(Kb + (size_t)(kbn + row) * HD + c4);
      }
#pragma unroll
      for (int i = 0; i < 4; ++i) {
        int d0 = (vg + i * 8) * 4;
        const float* vp0 = Vb + (size_t)(kbn + vkp) * HD + d0;
        vreg[2 * i] = *(const float4*)vp0;
        vreg[2 * i + 1] = *(const float4*)(vp0 + HD);
      }
    }

    f32x4 s[4];
#pragma unroll
    for (int ct = 0; ct < 4; ++ct) { s[ct][0]=0.f; s[ct][1]=0.f; s[ct][2]=0.f; s[ct][3]=0.f; }
#pragma unroll
    for (int kf = 0; kf < 4; ++kf)
#pragma unroll
      for (int ct = 0; ct < 4; ++ct) {
        bf16x8 ak = *(const bf16x8*)&Ksh[ct * 16 + l15][kf * 32 + quad * 8];
        s[ct] = __builtin_amdgcn_mfma_f32_16x16x32_bf16(ak, aq[kf], s[ct], 0, 0, 0);
      }

    float mx = s[0][0];
#pragma unroll
    for (int ct = 0; ct < 4; ++ct)
#pragma unroll
      for (int r = 0; r < 4; ++r) mx = fmaxf(mx, s[ct][r]);
    mx = fmaxf(mx, __shfl_xor(mx, 16));
    mx = fmaxf(mx, __shfl_xor(mx, 32));
    float mnew = fmaxf(m_r, mx);
    float alpha = __expf(m_r - mnew);
    m_r = mnew;
    float ls = 0.f;
#pragma unroll
    for (int ct = 0; ct < 4; ++ct)
#pragma unroll
      for (int r = 0; r < 4; ++r) {
        float p = __expf(s[ct][r] - mnew);
        s[ct][r] = p; ls += p;
      }
    ls += __shfl_xor(ls, 16);
    ls += __shfl_xor(ls, 32);
    l_r = l_r * alpha + ls;

#pragma unroll
    for (int ct = 0; ct < 4; ++ct) {
      bf16x4 pp;
      pp[0]=(bf16_t)s[ct][0]; pp[1]=(bf16_t)s[ct][1];
      pp[2]=(bf16_t)s[ct][2]; pp[3]=(bf16_t)s[ct][3];
      *(bf16x4*)&Psh[wq][l15][ct * 16 + quad * 4] = pp;
    }
    asm volatile("s_waitcnt lgkmcnt(0)" ::: "memory");
    bf16x8 ap0 = *(const bf16x8*)&Psh[wq][l15][quad * 8];
    bf16x8 ap1 = *(const bf16x8*)&Psh[wq][l15][32 + quad * 8];

#pragma unroll
    for (int t = 0; t < 8; ++t) {
      o[t][0]*=alpha; o[t][1]*=alpha; o[t][2]*=alpha; o[t][3]*=alpha;
    }
#pragma unroll
    for (int t = 0; t < 8; ++t) {
      bf16x8 av0 = *(const bf16x8*)&Vsh[t * 16 + l15][quad * 8];
      o[t] = __builtin_amdgcn_mfma_f32_16x16x32_bf16(av0, ap0, o[t], 0, 0, 0);
      bf16x8 av1 = *(const bf16x8*)&Vsh[t * 16 + l15][32 + quad * 8];
      o[t] = __builtin_amdgcn_mfma_f32_16x16x32_bf16(av1, ap1, o[t], 0, 0, 0);
    }
  }

  float inv = 1.0f / l_r;
  const int qrow = wq * 16 + l15;
#pragma unroll
  for (int t = 0; t < 8; ++t) {
    float4 w;
    w.x = o[t][0]*inv; w.y = o[t][1]*inv; w.z = o[t][2]*inv; w.w = o[t][3]*inv;
    *(float4*)&Ob[(size_t)qrow * HD + t * 16 + quad * 4] = w;
  }
}

extern "C" void kernel_launch(void* const* d_in, const int* in_sizes, int n_in,
                              void* d_out, int out_size, void* d_ws, size_t ws_size,
                              hipStream_t stream) {
  const float* q = (const float*)d_in[0];
  const float* k = (const float*)d_in[1];
  const float* v = (const float*)d_in[2];
  float* out = (float*)d_out;

  const size_t elems = (size_t)NB * SEQ * HD;          // 8388608
  const size_t need = elems * 2 * 2;                   // Kb + Vt bf16 = 32 MiB

  if (ws_size >= need) {
    bf16_t* Kb = (bf16_t*)d_ws;
    bf16_t* Vt = Kb + elems;
    prep_kernel<<<4096, 256, 0, stream>>>(k, v, Kb, Vt);
    fa15_kernel<<<NB * (SEQ / 64), 256, 0, stream>>>(q, Kb, Vt, out);
  } else {
    fa_fallback<<<NB * (SEQ / BM), 256, 0, stream>>>(q, k, v, out);
  }
}

// Round 11
// 222.385 us; speedup vs baseline: 1.2149x; 1.0119x over previous
//
#include <hip/hip_runtime.h>
#include <math.h>
#include <stdint.h>

typedef __bf16 bf16_t;
typedef __bf16 bf16x2 __attribute__((ext_vector_type(2)));
typedef __bf16 bf16x4 __attribute__((ext_vector_type(4)));
typedef __bf16 bf16x8 __attribute__((ext_vector_type(8)));
typedef float f32x4 __attribute__((ext_vector_type(4)));
typedef float f32x16 __attribute__((ext_vector_type(16)));

#define NB   32
#define SEQ  2048
#define HD   128
#define SCALE 0.08838834764831845f
#define LOG2E 1.4426950408889634f

__device__ __forceinline__ float fast_exp2(float x) {
#if __has_builtin(__builtin_amdgcn_exp2f)
  return __builtin_amdgcn_exp2f(x);
#else
  return exp2f(x);
#endif
}

// ============================ prep kernel =================================
// blocks 0..2047:    Kb = bf16(K)                 (Q converted inline in fa16)
// blocks 2048..4095: Vt = bf16(V) transposed [B][D][S], conflict-free f32 tile
__global__ __launch_bounds__(256) void prep_kernel(
    const float* __restrict__ K, const float* __restrict__ V,
    bf16_t* __restrict__ Kb, bf16_t* __restrict__ Vt)
{
  const int b = blockIdx.x;
  const int tid = threadIdx.x;
  if (b < 2048) {
    size_t base4 = (size_t)b * 1024;
#pragma unroll
    for (int i = 0; i < 4; ++i) {
      size_t idx = base4 + tid + i * 256;
      float4 x = ((const float4*)K)[idx];
      bf16x4 y;
      y[0] = (bf16_t)x.x; y[1] = (bf16_t)x.y;
      y[2] = (bf16_t)x.z; y[3] = (bf16_t)x.w;
      ((bf16x4*)Kb)[idx] = y;
    }
  } else {
    // f32 tile, stride 65: bank(s,d) = (s + d) % 32 -> conflict-free both sides.
    __shared__ float tile[64][65];  // 16.6 KB
    const int bt = b - 2048;
    const int batch = bt >> 6;
    const int rem = bt & 63;
    const int s0 = (rem >> 1) * 64;
    const int d0 = (rem & 1) * 64;
#pragma unroll
    for (int i = 0; i < 4; ++i) {
      int e = tid + i * 256;
      int s = e >> 4, dq = e & 15;
      float4 x = *(const float4*)&V[((size_t)batch * SEQ + s0 + s) * HD + d0 + dq * 4];
      tile[s][dq * 4 + 0] = x.x;
      tile[s][dq * 4 + 1] = x.y;
      tile[s][dq * 4 + 2] = x.z;
      tile[s][dq * 4 + 3] = x.w;
    }
    __syncthreads();
#pragma unroll
    for (int i = 0; i < 2; ++i) {
      int g = tid + i * 256;
      int d = g >> 3, sg = g & 7;
      bf16x8 w;
#pragma unroll
      for (int j = 0; j < 8; ++j) w[j] = (bf16_t)tile[sg * 8 + j][d];
      *(bf16x8*)&Vt[((size_t)batch * HD + d0 + d) * SEQ + s0 + sg * 8] = w;
    }
  }
}

// ============================ main kernel =================================
// fa16 = fa14 schedule (NO setprio — round-10 isolated it as the regressor:
// raising priority across the MFMA cluster starves the co-resident block's
// staging waves, m190 regime) + the two banked fa15 increments:
//   (a) Q read inline from fp32 (SCALE*LOG2E folded) -> prep has no Q pass.
//   (b) tree row-max (depth 4, max3-fusable; fmax exactly associative).
// Core (proven 113.3us): 32x32x16 MFMA, split-K pairs, in-register P via
// 4x shfl_xor, lagged PV(t-1), triple-buffered V, bijective XCD swizzle.
__global__ __launch_bounds__(256) void fa16_kernel(
    const float* __restrict__ Q, const bf16_t* __restrict__ Kbf,
    const bf16_t* __restrict__ Vt, float* __restrict__ O)
{
  __shared__ __attribute__((aligned(16))) char smem[81920];  // 80 KB exactly
  bf16_t* const Ksw = (bf16_t*)smem;               // 2 x 8192 bf16 (32 KB)
  bf16_t* const Vsw = (bf16_t*)(smem + 32768);     // 3 x 8192 bf16 (48 KB)

  const int tid  = threadIdx.x;
  const int lane = tid & 63;
  const int wq   = tid >> 6;
  const int hi   = lane >> 5;        // half of wave
  const int q31  = lane & 31;        // q-column within 32-row q-group
  const int pair = wq >> 1;          // 0: q 0-31, 1: q 32-63
  const int sub  = wq & 1;           // k-half within pair
  const int koff = sub * 32;

  // bijective XCD swizzle: 1024 blocks -> XCD x gets logical [x*128, x*128+128)
  const int L     = ((blockIdx.x & 7) << 7) | (blockIdx.x >> 3);
  const int batch = L >> 5;
  const int qt    = L & 31;

  const float*  Qb = Q   + ((size_t)batch * SEQ + qt * 64 + pair * 32) * HD;
  const bf16_t* Kb = Kbf + (size_t)batch * SEQ * HD;
  const bf16_t* Vb = Vt  + (size_t)batch * HD * SEQ;
  float*        Ob = O   + ((size_t)batch * SEQ + qt * 64) * HD;

  // ---- Q fragments from fp32, SCALE*LOG2E folded (B-operand):
  //      B[col=q31][k=d = dc*16 + hi*8 + j] ----
  bf16x8 bq[8];
  {
    const float qs = SCALE * LOG2E;
#pragma unroll
    for (int dc = 0; dc < 8; ++dc) {
      const float* qp = Qb + (size_t)q31 * HD + dc * 16 + hi * 8;
      float4 x0 = *(const float4*)qp;
      float4 x1 = *(const float4*)(qp + 4);
      bf16x8 a;
      a[0] = (bf16_t)(x0.x * qs); a[1] = (bf16_t)(x0.y * qs);
      a[2] = (bf16_t)(x0.z * qs); a[3] = (bf16_t)(x0.w * qs);
      a[4] = (bf16_t)(x1.x * qs); a[5] = (bf16_t)(x1.y * qs);
      a[6] = (bf16_t)(x1.z * qs); a[7] = (bf16_t)(x1.w * qs);
      bq[dc] = a;
    }
  }

  f32x16 o[4];
#pragma unroll
  for (int dt = 0; dt < 4; ++dt)
#pragma unroll
    for (int r = 0; r < 16; ++r) o[dt][r] = 0.f;
  float m_r = -INFINITY, l_r = 0.0f;

  // P fragments of previous tile (PV B-operands), carried across iterations
  bf16x8 bp0p, bp1p;

  // ---- DMA staging: wave stages 16 K-rows + 32 V-rows per tile ----
  auto stage = [&](int kbuf, int vbuf, int kb) {
#pragma unroll
    for (int i = 0; i < 4; ++i) {
      int row = wq * 16 + i * 4 + (lane >> 4);
      int gk = (lane & 15) ^ (row & 15);
      const bf16_t* gp = Kb + (size_t)(kb + row) * HD + gk * 8;
      __builtin_amdgcn_global_load_lds(
          (const __attribute__((address_space(1))) void*)gp,
          (__attribute__((address_space(3))) void*)&Ksw[kbuf * 8192 + (wq * 16 + i * 4) * 128],
          16, 0, 0);
    }
#pragma unroll
    for (int i = 0; i < 4; ++i) {
      int d = wq * 32 + i * 8 + (lane >> 3);
      int gv = (lane & 7) ^ (d & 7);
      const bf16_t* gp = Vb + (size_t)d * SEQ + kb + gv * 8;
      __builtin_amdgcn_global_load_lds(
          (const __attribute__((address_space(1))) void*)gp,
          (__attribute__((address_space(3))) void*)&Vsw[vbuf * 8192 + (wq * 32 + i * 8) * 64],
          16, 0, 0);
    }
  };

  stage(0, 0, 0);   // tile 0: K buf 0, V buf 0

  for (int t = 0; t < SEQ / 64; ++t) {
    __syncthreads();  // drains own DMA + all prior LDS reads (protects rotation)
    const int vnext = (t + 1) % 3;
    const int vprev = (t + 2) % 3;   // == (t-1) mod 3
    if (t + 1 < SEQ / 64) stage((t + 1) & 1, vnext, (t + 1) * 64);

    const bf16_t* Ks = &Ksw[(t & 1) * 8192];

    // ---- S^T = K Q^T on this wave's 32-k half (log2 units) ----
    f32x16 s;
#pragma unroll
    for (int r = 0; r < 16; ++r) s[r] = 0.f;
    {
      const int row = koff + q31;
      const int rsw = row & 15;
#pragma unroll
      for (int dc = 0; dc < 8; ++dc) {
        bf16x8 ak = *(const bf16x8*)&Ks[row * 128 + (((dc * 2 + hi) ^ rsw) * 8)];
        s = __builtin_amdgcn_mfma_f32_32x32x16_bf16(ak, bq[dc], s, 0, 0, 0);
      }
    }

    // ---- lagged PV(t-1): independent of s; fills the QK->softmax gap ----
    if (t > 0) {
      const bf16_t* Vp = &Vsw[vprev * 8192];
      const int g0 = (koff >> 3) + hi;
      const int g1 = g0 + 2;
#pragma unroll
      for (int dt = 0; dt < 4; ++dt) {
        const int d = dt * 32 + q31;
        const int dsw = d & 7;
        bf16x8 av0 = *(const bf16x8*)&Vp[d * 64 + ((g0 ^ dsw) * 8)];
        o[dt] = __builtin_amdgcn_mfma_f32_32x32x16_bf16(av0, bp0p, o[dt], 0, 0, 0);
        bf16x8 av1 = *(const bf16x8*)&Vp[d * 64 + ((g1 ^ dsw) * 8)];
        o[dt] = __builtin_amdgcn_mfma_f32_32x32x16_bf16(av1, bp1p, o[dt], 0, 0, 0);
      }
    }

    // ---- softmax: tree row max across this wave's 32 k (max3-fusable) ----
    float ma = fmaxf(fmaxf(s[0],  s[1]),  fmaxf(s[2],  s[3]));
    float mb = fmaxf(fmaxf(s[4],  s[5]),  fmaxf(s[6],  s[7]));
    float mc = fmaxf(fmaxf(s[8],  s[9]),  fmaxf(s[10], s[11]));
    float md = fmaxf(fmaxf(s[12], s[13]), fmaxf(s[14], s[15]));
    float mx = fmaxf(fmaxf(ma, mb), fmaxf(mc, md));
    mx = fmaxf(mx, __shfl_xor(mx, 32));

    // ---- defer-max: rescale only when max grew by > 8 (P bounded by 256) ----
    if (!__all(mx <= m_r + 8.0f)) {
      const float mnew = fmaxf(m_r, mx);
      const float alpha = fast_exp2(m_r - mnew);
      m_r = mnew;
      l_r *= alpha;
#pragma unroll
      for (int dt = 0; dt < 4; ++dt) o[dt] = o[dt] * alpha;
    }

    // ---- P = exp2(S - m), partial row sum (fa14-identical order) ----
    float ls = 0.f;
#pragma unroll
    for (int r = 0; r < 16; ++r) {
      float p = fast_exp2(s[r] - m_r);
      s[r] = p; ls += p;
    }
    ls += __shfl_xor(ls, 32);
    l_r += ls;

    // ---- pack P to bf16 pairs; assemble PV B-fragments via 4 shfl_xor ----
    uint32_t pk[8];
#pragma unroll
    for (int i = 0; i < 8; ++i) {
      union { bf16x2 v; uint32_t u; } c;
      c.v[0] = (bf16_t)s[2 * i];
      c.v[1] = (bf16_t)s[2 * i + 1];
      pk[i] = c.u;
    }
    uint32_t t0 = __shfl_xor((int)(hi ? pk[0] : pk[2]), 32);
    uint32_t t1 = __shfl_xor((int)(hi ? pk[1] : pk[3]), 32);
    uint32_t t2 = __shfl_xor((int)(hi ? pk[4] : pk[6]), 32);
    uint32_t t3 = __shfl_xor((int)(hi ? pk[5] : pk[7]), 32);
    {
      union { bf16x8 v; uint32_t w[4]; } B;
      if (hi) { B.w[0] = t0; B.w[1] = t1; B.w[2] = pk[2]; B.w[3] = pk[3]; }
      else    { B.w[0] = pk[0]; B.w[1] = pk[1]; B.w[2] = t0; B.w[3] = t1; }
      bp0p = B.v;
      if (hi) { B.w[0] = t2; B.w[1] = t3; B.w[2] = pk[6]; B.w[3] = pk[7]; }
      else    { B.w[0] = pk[4]; B.w[1] = pk[5]; B.w[2] = t2; B.w[3] = t3; }
      bp1p = B.v;
    }
  }

  // ---- final PV(T-1): V in buffer (T-1)%3, staged at iter T-2, drained ----
  {
    const bf16_t* Vp = &Vsw[((SEQ / 64 - 1) % 3) * 8192];
    const int g0 = (koff >> 3) + hi;
    const int g1 = g0 + 2;
#pragma unroll
    for (int dt = 0; dt < 4; ++dt) {
      const int d = dt * 32 + q31;
      const int dsw = d & 7;
      bf16x8 av0 = *(const bf16x8*)&Vp[d * 64 + ((g0 ^ dsw) * 8)];
      o[dt] = __builtin_amdgcn_mfma_f32_32x32x16_bf16(av0, bp0p, o[dt], 0, 0, 0);
      bf16x8 av1 = *(const bf16x8*)&Vp[d * 64 + ((g1 ^ dsw) * 8)];
      o[dt] = __builtin_amdgcn_mfma_f32_32x32x16_bf16(av1, bp1p, o[dt], 0, 0, 0);
    }
  }

  // ================= epilogue: merge k-halves, store =================
  __syncthreads();  // all loop/final-PV LDS reads done; alias smem as scratch
  float* const sf  = (float*)smem;              // pair*4224 + q*132 + d
  float* const mlb = (float*)(smem + 33792);    // 2 pairs x {m[32], l[32]}

  if (sub == 1) {
    if (hi == 0) {
      mlb[pair * 64 + q31]      = m_r;
      mlb[pair * 64 + 32 + q31] = l_r;
    }
#pragma unroll
    for (int dt = 0; dt < 4; ++dt)
#pragma unroll
      for (int r = 0; r < 16; ++r) {
        int d = dt * 32 + (r & 3) + 8 * (r >> 2) + 4 * hi;
        sf[pair * 4224 + q31 * 132 + d] = o[dt][r];
      }
  }
  __syncthreads();
  if (sub == 0) {
    float m1 = mlb[pair * 64 + q31];
    float l1 = mlb[pair * 64 + 32 + q31];
    float m = fmaxf(m_r, m1);
    float e0 = fast_exp2(m_r - m);
    float e1 = fast_exp2(m1 - m);
    float inv = 1.0f / (l_r * e0 + l1 * e1);
    float f0 = e0 * inv, f1 = e1 * inv;
#pragma unroll
    for (int dt = 0; dt < 4; ++dt)
#pragma unroll
      for (int r = 0; r < 16; ++r) {
        int d = dt * 32 + (r & 3) + 8 * (r >> 2) + 4 * hi;
        float* p = &sf[pair * 4224 + q31 * 132 + d];
        *p = o[dt][r] * f0 + *p * f1;
      }
  }
  __syncthreads();
  // cooperative coalesced store: 128 threads per pair, 8 float4 each
  {
    const int tid2 = sub * 64 + lane;   // 0..127 within pair
#pragma unroll
    for (int i = 0; i < 8; ++i) {
      int idx = tid2 + i * 128;         // 0..1023
      int q = idx >> 5;
      int dg = idx & 31;
      float4 v = *(const float4*)&sf[pair * 4224 + q * 132 + dg * 4];
      *(float4*)&Ob[(size_t)(pair * 32 + q) * HD + dg * 4] = v;
    }
  }
}

// ===================== fallback (proven R2 kernel) ========================
#define BM   64
#define BN   64
#define KPAD 8
#define VPAD 8
#define PPAD 8

__global__ __launch_bounds__(256) void fa_fallback(
    const float* __restrict__ Q, const float* __restrict__ K,
    const float* __restrict__ V, float* __restrict__ O)
{
  __shared__ __attribute__((aligned(16))) bf16_t Ksh[BN][HD + KPAD];
  __shared__ __attribute__((aligned(16))) bf16_t Vsh[HD][BN + VPAD];
  __shared__ __attribute__((aligned(16))) bf16_t Psh[4][16][BN + PPAD];

  const int tid = threadIdx.x;
  const int lane = tid & 63;
  const int wq = tid >> 6;
  const int quad = lane >> 4;
  const int l15 = lane & 15;
  const int bid = blockIdx.x;
  const int batch = bid >> 5;
  const int qt = bid & 31;

  const float* Qb = Q + (size_t)batch * SEQ * HD + (size_t)qt * BM * HD;
  const float* Kb = K + (size_t)batch * SEQ * HD;
  const float* Vb = V + (size_t)batch * SEQ * HD;
  float* Ob = O + (size_t)batch * SEQ * HD + (size_t)qt * BM * HD;

  bf16x8 aq[4];
  {
    const int qrow = wq * 16 + l15;
#pragma unroll
    for (int kf = 0; kf < 4; ++kf) {
      const float* qp = Qb + (size_t)qrow * HD + kf * 32 + quad * 8;
      float4 x0 = *(const float4*)(qp);
      float4 x1 = *(const float4*)(qp + 4);
      bf16x8 a;
      a[0] = (bf16_t)(x0.x * SCALE); a[1] = (bf16_t)(x0.y * SCALE);
      a[2] = (bf16_t)(x0.z * SCALE); a[3] = (bf16_t)(x0.w * SCALE);
      a[4] = (bf16_t)(x1.x * SCALE); a[5] = (bf16_t)(x1.y * SCALE);
      a[6] = (bf16_t)(x1.z * SCALE); a[7] = (bf16_t)(x1.w * SCALE);
      aq[kf] = a;
    }
  }

  f32x4 o[8];
#pragma unroll
  for (int t = 0; t < 8; ++t) { o[t][0]=0.f; o[t][1]=0.f; o[t][2]=0.f; o[t][3]=0.f; }
  float m_r = -INFINITY, l_r = 0.0f;
  const int vkp = (tid & 31) * 2;
  const int vg = tid >> 5;
  float4 kreg[8], vreg[8];

#pragma unroll
  for (int i = 0; i < 8; ++i) {
    int v = tid + i * 256, row = v >> 5, c4 = (v & 31) * 4;
    kreg[i] = *(const float4*)(Kb + (size_t)row * HD + c4);
  }
#pragma unroll
  for (int i = 0; i < 4; ++i) {
    int d0 = (vg + i * 8) * 4;
    const float* vp0 = Vb + (size_t)vkp * HD + d0;
    vreg[2 * i] = *(const float4*)vp0;
    vreg[2 * i + 1] = *(const float4*)(vp0 + HD);
  }

  for (int kb = 0; kb < SEQ; kb += BN) {
    __syncthreads();
#pragma unroll
    for (int i = 0; i < 8; ++i) {
      int v = tid + i * 256, row = v >> 5, c4 = (v & 31) * 4;
      float4 kv = kreg[i];
      bf16x4 kk;
      kk[0]=(bf16_t)kv.x; kk[1]=(bf16_t)kv.y; kk[2]=(bf16_t)kv.z; kk[3]=(bf16_t)kv.w;
      *(bf16x4*)&Ksh[row][c4] = kk;
    }
#pragma unroll
    for (int i = 0; i < 4; ++i) {
      int d0 = (vg + i * 8) * 4;
      float4 a0 = vreg[2 * i], a1 = vreg[2 * i + 1];
      bf16x2 p0; p0[0]=(bf16_t)a0.x; p0[1]=(bf16_t)a1.x;
      bf16x2 p1; p1[0]=(bf16_t)a0.y; p1[1]=(bf16_t)a1.y;
      bf16x2 p2; p2[0]=(bf16_t)a0.z; p2[1]=(bf16_t)a1.z;
      bf16x2 p3; p3[0]=(bf16_t)a0.w; p3[1]=(bf16_t)a1.w;
      *(bf16x2*)&Vsh[d0 + 0][vkp] = p0;
      *(bf16x2*)&Vsh[d0 + 1][vkp] = p1;
      *(bf16x2*)&Vsh[d0 + 2][vkp] = p2;
      *(bf16x2*)&Vsh[d0 + 3][vkp] = p3;
    }
    __syncthreads();

    const int kbn = kb + BN;
    if (kbn < SEQ) {
#pragma unroll
      for (int i = 0; i < 8; ++i) {
        int v = tid + i * 256, row = v >> 5, c4 = (v & 31) * 4;
        kreg[i] = *(const float4*)(Kb + (size_t)(kbn + row) * HD + c4);
      }
#pragma unroll
      for (int i = 0; i < 4; ++i) {
        int d0 = (vg + i * 8) * 4;
        const float* vp0 = Vb + (size_t)(kbn + vkp) * HD + d0;
        vreg[2 * i] = *(const float4*)vp0;
        vreg[2 * i + 1] = *(const float4*)(vp0 + HD);
      }
    }

    f32x4 s[4];
#pragma unroll
    for (int ct = 0; ct < 4; ++ct) { s[ct][0]=0.f; s[ct][1]=0.f; s[ct][2]=0.f; s[ct][3]=0.f; }
#pragma unroll
    for (int kf = 0; kf < 4; ++kf)
#pragma unroll
      for (int ct = 0; ct < 4; ++ct) {
        bf16x8 ak = *(const bf16x8*)&Ksh[ct * 16 + l15][kf * 32 + quad * 8];
        s[ct] = __builtin_amdgcn_mfma_f32_16x16x32_bf16(ak, aq[kf], s[ct], 0, 0, 0);
      }

    float mx = s[0][0];
#pragma unroll
    for (int ct = 0; ct < 4; ++ct)
#pragma unroll
      for (int r = 0; r < 4; ++r) mx = fmaxf(mx, s[ct][r]);
    mx = fmaxf(mx, __shfl_xor(mx, 16));
    mx = fmaxf(mx, __shfl_xor(mx, 32));
    float mnew = fmaxf(m_r, mx);
    float alpha = __expf(m_r - mnew);
    m_r = mnew;
    float ls = 0.f;
#pragma unroll
    for (int ct = 0; ct < 4; ++ct)
#pragma unroll
      for (int r = 0; r < 4; ++r) {
        float p = __expf(s[ct][r] - mnew);
        s[ct][r] = p; ls += p;
      }
    ls += __shfl_xor(ls, 16);
    ls += __shfl_xor(ls, 32);
    l_r = l_r * alpha + ls;

#pragma unroll
    for (int ct = 0; ct < 4; ++ct) {
      bf16x4 pp;
      pp[0]=(bf16_t)s[ct][0]; pp[1]=(bf16_t)s[ct][1];
      pp[2]=(bf16_t)s[ct][2]; pp[3]=(bf16_t)s[ct][3];
      *(bf16x4*)&Psh[wq][l15][ct * 16 + quad * 4] = pp;
    }
    asm volatile("s_waitcnt lgkmcnt(0)" ::: "memory");
    bf16x8 ap0 = *(const bf16x8*)&Psh[wq][l15][quad * 8];
    bf16x8 ap1 = *(const bf16x8*)&Psh[wq][l15][32 + quad * 8];

#pragma unroll
    for (int t = 0; t < 8; ++t) {
      o[t][0]*=alpha; o[t][1]*=alpha; o[t][2]*=alpha; o[t][3]*=alpha;
    }
#pragma unroll
    for (int t = 0; t < 8; ++t) {
      bf16x8 av0 = *(const bf16x8*)&Vsh[t * 16 + l15][quad * 8];
      o[t] = __builtin_amdgcn_mfma_f32_16x16x32_bf16(av0, ap0, o[t], 0, 0, 0);
      bf16x8 av1 = *(const bf16x8*)&Vsh[t * 16 + l15][32 + quad * 8];
      o[t] = __builtin_amdgcn_mfma_f32_16x16x32_bf16(av1, ap1, o[t], 0, 0, 0);
    }
  }

  float inv = 1.0f / l_r;
  const int qrow = wq * 16 + l15;
#pragma unroll
  for (int t = 0; t < 8; ++t) {
    float4 w;
    w.x = o[t][0]*inv; w.y = o[t][1]*inv; w.z = o[t][2]*inv; w.w = o[t][3]*inv;
    *(float4*)&Ob[(size_t)qrow * HD + t * 16 + quad * 4] = w;
  }
}

extern "C" void kernel_launch(void* const* d_in, const int* in_sizes, int n_in,
                              void* d_out, int out_size, void* d_ws, size_t ws_size,
                              hipStream_t stream) {
  const float* q = (const float*)d_in[0];
  const float* k = (const float*)d_in[1];
  const float* v = (const float*)d_in[2];
  float* out = (float*)d_out;

  const size_t elems = (size_t)NB * SEQ * HD;          // 8388608
  const size_t need = elems * 2 * 2;                   // Kb + Vt bf16 = 32 MiB

  if (ws_size >= need) {
    bf16_t* Kb = (bf16_t*)d_ws;
    bf16_t* Vt = Kb + elems;
    prep_kernel<<<4096, 256, 0, stream>>>(k, v, Kb, Vt);
    fa16_kernel<<<NB * (SEQ / 64), 256, 0, stream>>>(q, Kb, Vt, out);
  } else {
    fa_fallback<<<NB * (SEQ / BM), 256, 0, stream>>>(q, k, v, out);
  }
}

// Round 12
// 220.015 us; speedup vs baseline: 1.2280x; 1.0108x over previous
//
#include <hip/hip_runtime.h>
#include <math.h>
#include <stdint.h>

typedef __bf16 bf16_t;
typedef __bf16 bf16x2 __attribute__((ext_vector_type(2)));
typedef __bf16 bf16x4 __attribute__((ext_vector_type(4)));
typedef __bf16 bf16x8 __attribute__((ext_vector_type(8)));
typedef float f32x4 __attribute__((ext_vector_type(4)));
typedef float f32x16 __attribute__((ext_vector_type(16)));

#define NB   32
#define SEQ  2048
#define HD   128
#define SCALE 0.08838834764831845f
#define LOG2E 1.4426950408889634f

__device__ __forceinline__ float fast_exp2(float x) {
#if __has_builtin(__builtin_amdgcn_exp2f)
  return __builtin_amdgcn_exp2f(x);
#else
  return exp2f(x);
#endif
}

// ============================ prep kernel =================================
// blocks 0..2047:    Kb = bf16(K)                 (Q converted inline in fa17)
// blocks 2048..4095: Vt = bf16(V) transposed [B][D][S], conflict-free f32 tile
__global__ __launch_bounds__(256) void prep_kernel(
    const float* __restrict__ K, const float* __restrict__ V,
    bf16_t* __restrict__ Kb, bf16_t* __restrict__ Vt)
{
  const int b = blockIdx.x;
  const int tid = threadIdx.x;
  if (b < 2048) {
    size_t base4 = (size_t)b * 1024;
#pragma unroll
    for (int i = 0; i < 4; ++i) {
      size_t idx = base4 + tid + i * 256;
      float4 x = ((const float4*)K)[idx];
      bf16x4 y;
      y[0] = (bf16_t)x.x; y[1] = (bf16_t)x.y;
      y[2] = (bf16_t)x.z; y[3] = (bf16_t)x.w;
      ((bf16x4*)Kb)[idx] = y;
    }
  } else {
    // f32 tile, stride 65: bank(s,d) = (s + d) % 32 -> conflict-free both sides.
    __shared__ float tile[64][65];  // 16.6 KB
    const int bt = b - 2048;
    const int batch = bt >> 6;
    const int rem = bt & 63;
    const int s0 = (rem >> 1) * 64;
    const int d0 = (rem & 1) * 64;
#pragma unroll
    for (int i = 0; i < 4; ++i) {
      int e = tid + i * 256;
      int s = e >> 4, dq = e & 15;
      float4 x = *(const float4*)&V[((size_t)batch * SEQ + s0 + s) * HD + d0 + dq * 4];
      tile[s][dq * 4 + 0] = x.x;
      tile[s][dq * 4 + 1] = x.y;
      tile[s][dq * 4 + 2] = x.z;
      tile[s][dq * 4 + 3] = x.w;
    }
    __syncthreads();
#pragma unroll
    for (int i = 0; i < 2; ++i) {
      int g = tid + i * 256;
      int d = g >> 3, sg = g & 7;
      bf16x8 w;
#pragma unroll
      for (int j = 0; j < 8; ++j) w[j] = (bf16_t)tile[sg * 8 + j][d];
      *(bf16x8*)&Vt[((size_t)batch * HD + d0 + d) * SEQ + s0 + sg * 8] = w;
    }
  }
}

// ============================ main kernel =================================
// fa17 = fa16 with the Q prologue made COALESCED via an LDS round-trip
// (round-11 isolated the fa15/fa16 kernel regression to the strided fp32
// Q read: 64 lanes x 32 distinct 512B-apart lines per instruction, ~2K
// fragmented transactions per block at block start).  Now: 2048 consecutive
// float4s loaded coalesced (8/thread) -> [64][132] f32 LDS tile -> per-lane
// fragment reads (4-way, one-time) + convert.  Post-prologue code is
// byte-identical to fa16 (= fa14 schedule, no setprio):
//   32x32x16 MFMA, split-K pairs, in-register P via 4x shfl_xor,
//   lagged PV(t-1), triple-buffered V, bijective XCD swizzle, tree-max,
//   defer-max, exp2 softmax.
__global__ __launch_bounds__(256) void fa17_kernel(
    const float* __restrict__ Q, const bf16_t* __restrict__ Kbf,
    const bf16_t* __restrict__ Vt, float* __restrict__ O)
{
  __shared__ __attribute__((aligned(16))) char smem[81920];  // 80 KB exactly
  bf16_t* const Ksw = (bf16_t*)smem;               // 2 x 8192 bf16 (32 KB)
  bf16_t* const Vsw = (bf16_t*)(smem + 32768);     // 3 x 8192 bf16 (48 KB)

  const int tid  = threadIdx.x;
  const int lane = tid & 63;
  const int wq   = tid >> 6;
  const int hi   = lane >> 5;        // half of wave
  const int q31  = lane & 31;        // q-column within 32-row q-group
  const int pair = wq >> 1;          // 0: q 0-31, 1: q 32-63
  const int sub  = wq & 1;           // k-half within pair
  const int koff = sub * 32;

  // bijective XCD swizzle: 1024 blocks -> XCD x gets logical [x*128, x*128+128)
  const int L     = ((blockIdx.x & 7) << 7) | (blockIdx.x >> 3);
  const int batch = L >> 5;
  const int qt    = L & 31;

  const bf16_t* Kb = Kbf + (size_t)batch * SEQ * HD;
  const bf16_t* Vb = Vt  + (size_t)batch * HD * SEQ;
  float*        Ob = O   + ((size_t)batch * SEQ + qt * 64) * HD;

  // ---- Q prologue: coalesced global->LDS, then per-lane fragment convert.
  //      bq = B-operand: B[col=q31][k=d = dc*16 + hi*8 + j], bf16(Q*qs). ----
  bf16x8 bq[8];
  {
    float* const qf = (float*)smem;            // [64][132] f32 = 33.8 KB
    const float* Qblk = Q + ((size_t)batch * SEQ + qt * 64) * HD;
#pragma unroll
    for (int i = 0; i < 8; ++i) {
      int idx = tid + i * 256;                 // 0..2047 consecutive float4s
      int row = idx >> 5, c4 = idx & 31;
      float4 x = ((const float4*)Qblk)[idx];
      *(float4*)&qf[row * 132 + c4 * 4] = x;
    }
    __syncthreads();
    const float qs = SCALE * LOG2E;
    const int qrow = pair * 32 + q31;
#pragma unroll
    for (int dc = 0; dc < 8; ++dc) {
      const float* qp = &qf[qrow * 132 + dc * 16 + hi * 8];
      float4 x0 = *(const float4*)qp;
      float4 x1 = *(const float4*)(qp + 4);
      bf16x8 a;
      a[0] = (bf16_t)(x0.x * qs); a[1] = (bf16_t)(x0.y * qs);
      a[2] = (bf16_t)(x0.z * qs); a[3] = (bf16_t)(x0.w * qs);
      a[4] = (bf16_t)(x1.x * qs); a[5] = (bf16_t)(x1.y * qs);
      a[6] = (bf16_t)(x1.z * qs); a[7] = (bf16_t)(x1.w * qs);
      bq[dc] = a;
    }
    __syncthreads();   // all qf reads done before staging overwrites smem
  }

  f32x16 o[4];
#pragma unroll
  for (int dt = 0; dt < 4; ++dt)
#pragma unroll
    for (int r = 0; r < 16; ++r) o[dt][r] = 0.f;
  float m_r = -INFINITY, l_r = 0.0f;

  // P fragments of previous tile (PV B-operands), carried across iterations
  bf16x8 bp0p, bp1p;

  // ---- DMA staging: wave stages 16 K-rows + 32 V-rows per tile ----
  auto stage = [&](int kbuf, int vbuf, int kb) {
#pragma unroll
    for (int i = 0; i < 4; ++i) {
      int row = wq * 16 + i * 4 + (lane >> 4);
      int gk = (lane & 15) ^ (row & 15);
      const bf16_t* gp = Kb + (size_t)(kb + row) * HD + gk * 8;
      __builtin_amdgcn_global_load_lds(
          (const __attribute__((address_space(1))) void*)gp,
          (__attribute__((address_space(3))) void*)&Ksw[kbuf * 8192 + (wq * 16 + i * 4) * 128],
          16, 0, 0);
    }
#pragma unroll
    for (int i = 0; i < 4; ++i) {
      int d = wq * 32 + i * 8 + (lane >> 3);
      int gv = (lane & 7) ^ (d & 7);
      const bf16_t* gp = Vb + (size_t)d * SEQ + kb + gv * 8;
      __builtin_amdgcn_global_load_lds(
          (const __attribute__((address_space(1))) void*)gp,
          (__attribute__((address_space(3))) void*)&Vsw[vbuf * 8192 + (wq * 32 + i * 8) * 64],
          16, 0, 0);
    }
  };

  stage(0, 0, 0);   // tile 0: K buf 0, V buf 0

  for (int t = 0; t < SEQ / 64; ++t) {
    __syncthreads();  // drains own DMA + all prior LDS reads (protects rotation)
    const int vnext = (t + 1) % 3;
    const int vprev = (t + 2) % 3;   // == (t-1) mod 3
    if (t + 1 < SEQ / 64) stage((t + 1) & 1, vnext, (t + 1) * 64);

    const bf16_t* Ks = &Ksw[(t & 1) * 8192];

    // ---- S^T = K Q^T on this wave's 32-k half (log2 units) ----
    f32x16 s;
#pragma unroll
    for (int r = 0; r < 16; ++r) s[r] = 0.f;
    {
      const int row = koff + q31;
      const int rsw = row & 15;
#pragma unroll
      for (int dc = 0; dc < 8; ++dc) {
        bf16x8 ak = *(const bf16x8*)&Ks[row * 128 + (((dc * 2 + hi) ^ rsw) * 8)];
        s = __builtin_amdgcn_mfma_f32_32x32x16_bf16(ak, bq[dc], s, 0, 0, 0);
      }
    }

    // ---- lagged PV(t-1): independent of s; fills the QK->softmax gap ----
    if (t > 0) {
      const bf16_t* Vp = &Vsw[vprev * 8192];
      const int g0 = (koff >> 3) + hi;
      const int g1 = g0 + 2;
#pragma unroll
      for (int dt = 0; dt < 4; ++dt) {
        const int d = dt * 32 + q31;
        const int dsw = d & 7;
        bf16x8 av0 = *(const bf16x8*)&Vp[d * 64 + ((g0 ^ dsw) * 8)];
        o[dt] = __builtin_amdgcn_mfma_f32_32x32x16_bf16(av0, bp0p, o[dt], 0, 0, 0);
        bf16x8 av1 = *(const bf16x8*)&Vp[d * 64 + ((g1 ^ dsw) * 8)];
        o[dt] = __builtin_amdgcn_mfma_f32_32x32x16_bf16(av1, bp1p, o[dt], 0, 0, 0);
      }
    }

    // ---- softmax: tree row max across this wave's 32 k (max3-fusable) ----
    float ma = fmaxf(fmaxf(s[0],  s[1]),  fmaxf(s[2],  s[3]));
    float mb = fmaxf(fmaxf(s[4],  s[5]),  fmaxf(s[6],  s[7]));
    float mc = fmaxf(fmaxf(s[8],  s[9]),  fmaxf(s[10], s[11]));
    float md = fmaxf(fmaxf(s[12], s[13]), fmaxf(s[14], s[15]));
    float mx = fmaxf(fmaxf(ma, mb), fmaxf(mc, md));
    mx = fmaxf(mx, __shfl_xor(mx, 32));

    // ---- defer-max: rescale only when max grew by > 8 (P bounded by 256) ----
    if (!__all(mx <= m_r + 8.0f)) {
      const float mnew = fmaxf(m_r, mx);
      const float alpha = fast_exp2(m_r - mnew);
      m_r = mnew;
      l_r *= alpha;
#pragma unroll
      for (int dt = 0; dt < 4; ++dt) o[dt] = o[dt] * alpha;
    }

    // ---- P = exp2(S - m), partial row sum ----
    float ls = 0.f;
#pragma unroll
    for (int r = 0; r < 16; ++r) {
      float p = fast_exp2(s[r] - m_r);
      s[r] = p; ls += p;
    }
    ls += __shfl_xor(ls, 32);
    l_r += ls;

    // ---- pack P to bf16 pairs; assemble PV B-fragments via 4 shfl_xor ----
    uint32_t pk[8];
#pragma unroll
    for (int i = 0; i < 8; ++i) {
      union { bf16x2 v; uint32_t u; } c;
      c.v[0] = (bf16_t)s[2 * i];
      c.v[1] = (bf16_t)s[2 * i + 1];
      pk[i] = c.u;
    }
    uint32_t t0 = __shfl_xor((int)(hi ? pk[0] : pk[2]), 32);
    uint32_t t1 = __shfl_xor((int)(hi ? pk[1] : pk[3]), 32);
    uint32_t t2 = __shfl_xor((int)(hi ? pk[4] : pk[6]), 32);
    uint32_t t3 = __shfl_xor((int)(hi ? pk[5] : pk[7]), 32);
    {
      union { bf16x8 v; uint32_t w[4]; } B;
      if (hi) { B.w[0] = t0; B.w[1] = t1; B.w[2] = pk[2]; B.w[3] = pk[3]; }
      else    { B.w[0] = pk[0]; B.w[1] = pk[1]; B.w[2] = t0; B.w[3] = t1; }
      bp0p = B.v;
      if (hi) { B.w[0] = t2; B.w[1] = t3; B.w[2] = pk[6]; B.w[3] = pk[7]; }
      else    { B.w[0] = pk[4]; B.w[1] = pk[5]; B.w[2] = t2; B.w[3] = t3; }
      bp1p = B.v;
    }
  }

  // ---- final PV(T-1): V in buffer (T-1)%3, staged at iter T-2, drained ----
  {
    const bf16_t* Vp = &Vsw[((SEQ / 64 - 1) % 3) * 8192];
    const int g0 = (koff >> 3) + hi;
    const int g1 = g0 + 2;
#pragma unroll
    for (int dt = 0; dt < 4; ++dt) {
      const int d = dt * 32 + q31;
      const int dsw = d & 7;
      bf16x8 av0 = *(const bf16x8*)&Vp[d * 64 + ((g0 ^ dsw) * 8)];
      o[dt] = __builtin_amdgcn_mfma_f32_32x32x16_bf16(av0, bp0p, o[dt], 0, 0, 0);
      bf16x8 av1 = *(const bf16x8*)&Vp[d * 64 + ((g1 ^ dsw) * 8)];
      o[dt] = __builtin_amdgcn_mfma_f32_32x32x16_bf16(av1, bp1p, o[dt], 0, 0, 0);
    }
  }

  // ================= epilogue: merge k-halves, store =================
  __syncthreads();  // all loop/final-PV LDS reads done; alias smem as scratch
  float* const sf  = (float*)smem;              // pair*4224 + q*132 + d
  float* const mlb = (float*)(smem + 33792);    // 2 pairs x {m[32], l[32]}

  if (sub == 1) {
    if (hi == 0) {
      mlb[pair * 64 + q31]      = m_r;
      mlb[pair * 64 + 32 + q31] = l_r;
    }
#pragma unroll
    for (int dt = 0; dt < 4; ++dt)
#pragma unroll
      for (int r = 0; r < 16; ++r) {
        int d = dt * 32 + (r & 3) + 8 * (r >> 2) + 4 * hi;
        sf[pair * 4224 + q31 * 132 + d] = o[dt][r];
      }
  }
  __syncthreads();
  if (sub == 0) {
    float m1 = mlb[pair * 64 + q31];
    float l1 = mlb[pair * 64 + 32 + q31];
    float m = fmaxf(m_r, m1);
    float e0 = fast_exp2(m_r - m);
    float e1 = fast_exp2(m1 - m);
    float inv = 1.0f / (l_r * e0 + l1 * e1);
    float f0 = e0 * inv, f1 = e1 * inv;
#pragma unroll
    for (int dt = 0; dt < 4; ++dt)
#pragma unroll
      for (int r = 0; r < 16; ++r) {
        int d = dt * 32 + (r & 3) + 8 * (r >> 2) + 4 * hi;
        float* p = &sf[pair * 4224 + q31 * 132 + d];
        *p = o[dt][r] * f0 + *p * f1;
      }
  }
  __syncthreads();
  // cooperative coalesced store: 128 threads per pair, 8 float4 each
  {
    const int tid2 = sub * 64 + lane;   // 0..127 within pair
#pragma unroll
    for (int i = 0; i < 8; ++i) {
      int idx = tid2 + i * 128;         // 0..1023
      int q = idx >> 5;
      int dg = idx & 31;
      float4 v = *(const float4*)&sf[pair * 4224 + q * 132 + dg * 4];
      *(float4*)&Ob[(size_t)(pair * 32 + q) * HD + dg * 4] = v;
    }
  }
}

// ===================== fallback (proven R2 kernel) ========================
#define BM   64
#define BN   64
#define KPAD 8
#define VPAD 8
#define PPAD 8

__global__ __launch_bounds__(256) void fa_fallback(
    const float* __restrict__ Q, const float* __restrict__ K,
    const float* __restrict__ V, float* __restrict__ O)
{
  __shared__ __attribute__((aligned(16))) bf16_t Ksh[BN][HD + KPAD];
  __shared__ __attribute__((aligned(16))) bf16_t Vsh[HD][BN + VPAD];
  __shared__ __attribute__((aligned(16))) bf16_t Psh[4][16][BN + PPAD];

  const int tid = threadIdx.x;
  const int lane = tid & 63;
  const int wq = tid >> 6;
  const int quad = lane >> 4;
  const int l15 = lane & 15;
  const int bid = blockIdx.x;
  const int batch = bid >> 5;
  const int qt = bid & 31;

  const float* Qb = Q + (size_t)batch * SEQ * HD + (size_t)qt * BM * HD;
  const float* Kb = K + (size_t)batch * SEQ * HD;
  const float* Vb = V + (size_t)batch * SEQ * HD;
  float* Ob = O + (size_t)batch * SEQ * HD + (size_t)qt * BM * HD;

  bf16x8 aq[4];
  {
    const int qrow = wq * 16 + l15;
#pragma unroll
    for (int kf = 0; kf < 4; ++kf) {
      const float* qp = Qb + (size_t)qrow * HD + kf * 32 + quad * 8;
      float4 x0 = *(const float4*)(qp);
      float4 x1 = *(const float4*)(qp + 4);
      bf16x8 a;
      a[0] = (bf16_t)(x0.x * SCALE); a[1] = (bf16_t)(x0.y * SCALE);
      a[2] = (bf16_t)(x0.z * SCALE); a[3] = (bf16_t)(x0.w * SCALE);
      a[4] = (bf16_t)(x1.x * SCALE); a[5] = (bf16_t)(x1.y * SCALE);
      a[6] = (bf16_t)(x1.z * SCALE); a[7] = (bf16_t)(x1.w * SCALE);
      aq[kf] = a;
    }
  }

  f32x4 o[8];
#pragma unroll
  for (int t = 0; t < 8; ++t) { o[t][0]=0.f; o[t][1]=0.f; o[t][2]=0.f; o[t][3]=0.f; }
  float m_r = -INFINITY, l_r = 0.0f;
  const int vkp = (tid & 31) * 2;
  const int vg = tid >> 5;
  float4 kreg[8], vreg[8];

#pragma unroll
  for (int i = 0; i < 8; ++i) {
    int v = tid + i * 256, row = v >> 5, c4 = (v & 31) * 4;
    kreg[i] = *(const float4*)(Kb + (size_t)row * HD + c4);
  }
#pragma unroll
  for (int i = 0; i < 4; ++i) {
    int d0 = (vg + i * 8) * 4;
    const float* vp0 = Vb + (size_t)vkp * HD + d0;
    vreg[2 * i] = *(const float4*)vp0;
    vreg[2 * i + 1] = *(const float4*)(vp0 + HD);
  }

  for (int kb = 0; kb < SEQ; kb += BN) {
    __syncthreads();
#pragma unroll
    for (int i = 0; i < 8; ++i) {
      int v = tid + i * 256, row = v >> 5, c4 = (v & 31) * 4;
      float4 kv = kreg[i];
      bf16x4 kk;
      kk[0]=(bf16_t)kv.x; kk[1]=(bf16_t)kv.y; kk[2]=(bf16_t)kv.z; kk[3]=(bf16_t)kv.w;
      *(bf16x4*)&Ksh[row][c4] = kk;
    }
#pragma unroll
    for (int i = 0; i < 4; ++i) {
      int d0 = (vg + i * 8) * 4;
      float4 a0 = vreg[2 * i], a1 = vreg[2 * i + 1];
      bf16x2 p0; p0[0]=(bf16_t)a0.x; p0[1]=(bf16_t)a1.x;
      bf16x2 p1; p1[0]=(bf16_t)a0.y; p1[1]=(bf16_t)a1.y;
      bf16x2 p2; p2[0]=(bf16_t)a0.z; p2[1]=(bf16_t)a1.z;
      bf16x2 p3; p3[0]=(bf16_t)a0.w; p3[1]=(bf16_t)a1.w;
      *(bf16x2*)&Vsh[d0 + 0][vkp] = p0;
      *(bf16x2*)&Vsh[d0 + 1][vkp] = p1;
      *(bf16x2*)&Vsh[d0 + 2][vkp] = p2;
      *(bf16x2*)&Vsh[d0 + 3][vkp] = p3;
    }
    __syncthreads();

    const int kbn = kb + BN;
    if (kbn < SEQ) {
#pragma unroll
      for (int i = 0; i < 8; ++i) {
        int v = tid + i * 256, row = v >> 5, c4 = (v & 31) * 4;
        kreg[i] = *(const float4*)(Kb + (size_t)(kbn + row) * HD + c4);
      }
#pragma unroll
      for (int i = 0; i < 4; ++i) {
        int d0 = (vg + i * 8) * 4;
        const float* vp0 = Vb + (size_t)(kbn + vkp) * HD + d0;
        vreg[2 * i] = *(const float4*)vp0;
        vreg[2 * i + 1] = *(const float4*)(vp0 + HD);
      }
    }

    f32x4 s[4];
#pragma unroll
    for (int ct = 0; ct < 4; ++ct) { s[ct][0]=0.f; s[ct][1]=0.f; s[ct][2]=0.f; s[ct][3]=0.f; }
#pragma unroll
    for (int kf = 0; kf < 4; ++kf)
#pragma unroll
      for (int ct = 0; ct < 4; ++ct) {
        bf16x8 ak = *(const bf16x8*)&Ksh[ct * 16 + l15][kf * 32 + quad * 8];
        s[ct] = __builtin_amdgcn_mfma_f32_16x16x32_bf16(ak, aq[kf], s[ct], 0, 0, 0);
      }

    float mx = s[0][0];
#pragma unroll
    for (int ct = 0; ct < 4; ++ct)
#pragma unroll
      for (int r = 0; r < 4; ++r) mx = fmaxf(mx, s[ct][r]);
    mx = fmaxf(mx, __shfl_xor(mx, 16));
    mx = fmaxf(mx, __shfl_xor(mx, 32));
    float mnew = fmaxf(m_r, mx);
    float alpha = __expf(m_r - mnew);
    m_r = mnew;
    float ls = 0.f;
#pragma unroll
    for (int ct = 0; ct < 4; ++ct)
#pragma unroll
      for (int r = 0; r < 4; ++r) {
        float p = __expf(s[ct][r] - mnew);
        s[ct][r] = p; ls += p;
      }
    ls += __shfl_xor(ls, 16);
    ls += __shfl_xor(ls, 32);
    l_r = l_r * alpha + ls;

#pragma unroll
    for (int ct = 0; ct < 4; ++ct) {
      bf16x4 pp;
      pp[0]=(bf16_t)s[ct][0]; pp[1]=(bf16_t)s[ct][1];
      pp[2]=(bf16_t)s[ct][2]; pp[3]=(bf16_t)s[ct][3];
      *(bf16x4*)&Psh[wq][l15][ct * 16 + quad * 4] = pp;
    }
    asm volatile("s_waitcnt lgkmcnt(0)" ::: "memory");
    bf16x8 ap0 = *(const bf16x8*)&Psh[wq][l15][quad * 8];
    bf16x8 ap1 = *(const bf16x8*)&Psh[wq][l15][32 + quad * 8];

#pragma unroll
    for (int t = 0; t < 8; ++t) {
      o[t][0]*=alpha; o[t][1]*=alpha; o[t][2]*=alpha; o[t][3]*=alpha;
    }
#pragma unroll
    for (int t = 0; t < 8; ++t) {
      bf16x8 av0 = *(const bf16x8*)&Vsh[t * 16 + l15][quad * 8];
      o[t] = __builtin_amdgcn_mfma_f32_16x16x32_bf16(av0, ap0, o[t], 0, 0, 0);
      bf16x8 av1 = *(const bf16x8*)&Vsh[t * 16 + l15][32 + quad * 8];
      o[t] = __builtin_amdgcn_mfma_f32_16x16x32_bf16(av1, ap1, o[t], 0, 0, 0);
    }
  }

  float inv = 1.0f / l_r;
  const int qrow = wq * 16 + l15;
#pragma unroll
  for (int t = 0; t < 8; ++t) {
    float4 w;
    w.x = o[t][0]*inv; w.y = o[t][1]*inv; w.z = o[t][2]*inv; w.w = o[t][3]*inv;
    *(float4*)&Ob[(size_t)qrow * HD + t * 16 + quad * 4] = w;
  }
}

extern "C" void kernel_launch(void* const* d_in, const int* in_sizes, int n_in,
                              void* d_out, int out_size, void* d_ws, size_t ws_size,
                              hipStream_t stream) {
  const float* q = (const float*)d_in[0];
  const float* k = (const float*)d_in[1];
  const float* v = (const float*)d_in[2];
  float* out = (float*)d_out;

  const size_t elems = (size_t)NB * SEQ * HD;          // 8388608
  const size_t need = elems * 2 * 2;                   // Kb + Vt bf16 = 32 MiB

  if (ws_size >= need) {
    bf16_t* Kb = (bf16_t*)d_ws;
    bf16_t* Vt = Kb + elems;
    prep_kernel<<<4096, 256, 0, stream>>>(k, v, Kb, Vt);
    fa17_kernel<<<NB * (SEQ / 64), 256, 0, stream>>>(q, Kb, Vt, out);
  } else {
    fa_fallback<<<NB * (SEQ / BM), 256, 0, stream>>>(q, k, v, out);
  }
}